// Round 9
// baseline (1280.456 us; speedup 1.0000x reference)
//
#include <hip/hip_runtime.h>

// GIN + virtual-node GNN, 5 layers.
// R9: (a) agg gathers h_in from a bf16 copy (h16) -> halves the dominant
//     ~150MB/dispatch gather traffic; self-term + vnsum stay fp32.
//     (b) agg writes t_pre pre-split as bf16 hi/lo (numerically identical to
//     gemm1's internal split) -> gemm1 A-staging is a pure copy.
//     XCD swizzle removed (R8: measured neutral, FETCH unchanged).

#define EMB 128
#define NGR 512
#define NLAYER 5
static constexpr float BN_EPS = 1e-5f;

typedef __attribute__((ext_vector_type(8))) short short8v;  // 8 bf16 = 4 VGPR
typedef __attribute__((ext_vector_type(4))) float f32x4;

__device__ __forceinline__ ushort f2bf(float f) {
  union { float f; unsigned u; } c; c.f = f;
  return (ushort)((c.u + 0x7FFFu + ((c.u >> 16) & 1u)) >> 16);
}
__device__ __forceinline__ float bf2f(ushort h) {
  union { unsigned u; float f; } c; c.u = ((unsigned)h) << 16;
  return c.f;
}

// ---------------- setup kernels ----------------

__global__ void init_kernel(int* __restrict__ deg, int ndeg,
                            float* __restrict__ stats, int nstats,
                            float* __restrict__ vn, const float* __restrict__ vn_emb) {
  int idx = blockIdx.x * blockDim.x + threadIdx.x;
  if (idx < ndeg) deg[idx] = 0;
  if (idx < nstats) stats[idx] = 0.f;
  if (idx < NGR * EMB) vn[idx] = vn_emb[idx & (EMB - 1)];
}

__global__ void deg_kernel(const int* __restrict__ ei, int* __restrict__ deg, int E) {
  int e = blockIdx.x * blockDim.x + threadIdx.x;
  if (e < E) atomicAdd(&deg[ei[E + e]], 1);
}

// ---- hierarchical prefix scan over deg[n] (2048 elems per 256-thr block) ----

__global__ void scan1_kernel(const int* __restrict__ deg, int* __restrict__ bsum, int n) {
  __shared__ int ws[4];
  int t = threadIdx.x;
  int base = blockIdx.x * 2048 + t * 8;
  int s = 0;
  #pragma unroll
  for (int i = 0; i < 8; ++i) {
    int idx = base + i;
    if (idx < n) s += deg[idx];
  }
  #pragma unroll
  for (int off = 32; off; off >>= 1) s += __shfl_down(s, off);
  if ((t & 63) == 0) ws[t >> 6] = s;
  __syncthreads();
  if (t == 0) bsum[blockIdx.x] = ws[0] + ws[1] + ws[2] + ws[3];
}

// single 64-thread block; nb <= 64. boff = exclusive scan; *row_n = total.
__global__ void scan2_kernel(const int* __restrict__ bsum, int* __restrict__ boff,
                             int* __restrict__ row_n, int nb) {
  int t = threadIdx.x;
  int mine = (t < nb) ? bsum[t] : 0;
  int v = mine;
  #pragma unroll
  for (int off = 1; off < 64; off <<= 1) {
    int u = __shfl_up(v, off);
    if (t >= off) v += u;
  }
  if (t < nb) boff[t] = v - mine;
  if (t == nb - 1) *row_n = v;
}

__global__ __launch_bounds__(256) void scan3_kernel(const int* __restrict__ deg,
                                                    const int* __restrict__ boff,
                                                    int* __restrict__ row_start,
                                                    int* __restrict__ cursor, int n) {
  __shared__ int lsum[256];
  int t = threadIdx.x;
  int base = blockIdx.x * 2048 + t * 8;
  int loc[8];
  int s = 0;
  #pragma unroll
  for (int i = 0; i < 8; ++i) {
    int idx = base + i;
    int d = (idx < n) ? deg[idx] : 0;
    loc[i] = s;
    s += d;
  }
  lsum[t] = s;
  __syncthreads();
  #pragma unroll
  for (int off = 1; off < 256; off <<= 1) {
    int v2 = (t >= off) ? lsum[t - off] : 0;
    __syncthreads();
    lsum[t] += v2;
    __syncthreads();
  }
  int toff = boff[blockIdx.x] + lsum[t] - s;  // exclusive across grid
  #pragma unroll
  for (int i = 0; i < 8; ++i) {
    int idx = base + i;
    if (idx < n) {
      int rs = toff + loc[i];
      row_start[idx] = rs;
      cursor[idx] = rs;
    }
  }
}

__global__ void fill_kernel(const int* __restrict__ ei, int* __restrict__ cursor,
                            int2* __restrict__ el, int E) {
  int e = blockIdx.x * blockDim.x + threadIdx.x;
  if (e < E) {
    int d = ei[E + e];
    int pos = atomicAdd(&cursor[d], 1);
    el[pos] = make_int2(e, ei[e]);   // (edge id, src)
  }
}

// graph_start[g] = lower_bound(batch, g); batch is sorted. Handles empty graphs.
__global__ void bounds_kernel(const int* __restrict__ batch, int* __restrict__ gstart,
                              int n, int ng) {
  int g = blockIdx.x * blockDim.x + threadIdx.x;
  if (g > ng) return;
  int lo = 0, hi = n;
  while (lo < hi) {
    int mid = (lo + hi) >> 1;
    if (batch[mid] < g) lo = mid + 1; else hi = mid;
  }
  gstart[g] = lo;
}

// W [L][K][N] -> Wth/Wtl [L][N][K] (transpose + bf16 hi/lo split), per flat idx
__global__ void wtrans_kernel(const float* __restrict__ W, ushort* __restrict__ Wth,
                              ushort* __restrict__ Wtl, int K, int N, int total) {
  int idx = blockIdx.x * blockDim.x + threadIdx.x;
  if (idx >= total) return;
  int kk = idx % K;
  int t = idx / K;
  int nn = t % N;
  int l = t / N;
  float v = W[((size_t)l * K + kk) * N + nn];
  ushort h = f2bf(v);
  Wth[idx] = h;
  Wtl[idx] = f2bf(v - bf2f(h));
}

// h0 = x @ node_W + node_b   (K=9, N=128)
__global__ void encoder_kernel(const float* __restrict__ x, const float* __restrict__ W,
                               const float* __restrict__ b, float* __restrict__ h0, int n) {
  __shared__ float Ws[9][EMB];
  __shared__ float bs[EMB];
  int t = threadIdx.x;
  if (t < EMB) {
    #pragma unroll
    for (int k = 0; k < 9; ++k) Ws[k][t] = W[k * EMB + t];
    bs[t] = b[t];
  }
  __syncthreads();
  int total = n * EMB;
  for (int idx = blockIdx.x * blockDim.x + t; idx < total; idx += gridDim.x * blockDim.x) {
    int i = idx >> 7, j = idx & 127;
    const float* xr = x + i * 9;
    float acc = bs[j];
    #pragma unroll
    for (int k = 0; k < 9; ++k) acc = fmaf(xr[k], Ws[k][j], acc);
    h0[idx] = acc;
  }
}

// ---------------- per-layer kernels ----------------

// h_in = (RAW ? src : relu(bn2(src))) + vn[batch]; also writes bf16 copy h16
template <bool RAW>
__global__ void hin_kernel(const float* __restrict__ src, const float* __restrict__ vn,
                           const int* __restrict__ batch, const float* __restrict__ s2raw,
                           const float* __restrict__ g2, const float* __restrict__ b2,
                           float* __restrict__ h_in, ushort* __restrict__ h16, int n) {
  __shared__ float sc[EMB], sh[EMB];
  if (!RAW) {
    int j = threadIdx.x;
    if (j < EMB) {
      float s = s2raw[j], q = s2raw[EMB + j];
      float mean = s / (float)n;
      float var = q / (float)n - mean * mean;
      float scl = g2[j] * rsqrtf(var + BN_EPS);
      sc[j] = scl;
      sh[j] = b2[j] - mean * scl;
    }
    __syncthreads();
  }
  int total = n * EMB;
  for (int idx = blockIdx.x * blockDim.x + threadIdx.x; idx < total; idx += gridDim.x * blockDim.x) {
    int i = idx >> 7, j = idx & 127;
    float v = src[idx];
    if (!RAW) v = fmaxf(fmaf(v, sc[j], sh[j]), 0.f);
    float hv = v + vn[batch[i] * EMB + j];
    h_in[idx] = hv;
    h16[idx] = f2bf(hv);
  }
}

// final output: d_out = bn2(t2)  (no relu, layer L-1)
__global__ void out_kernel(const float* __restrict__ t2, const float* __restrict__ s2raw,
                           const float* __restrict__ g2, const float* __restrict__ b2,
                           float* __restrict__ out, int n) {
  __shared__ float sc[EMB], sh[EMB];
  int j0 = threadIdx.x;
  if (j0 < EMB) {
    float s = s2raw[j0], q = s2raw[EMB + j0];
    float mean = s / (float)n;
    float var = q / (float)n - mean * mean;
    float scl = g2[j0] * rsqrtf(var + BN_EPS);
    sc[j0] = scl;
    sh[j0] = b2[j0] - mean * scl;
  }
  __syncthreads();
  int total = n * EMB;
  for (int idx = blockIdx.x * blockDim.x + threadIdx.x; idx < total; idx += gridDim.x * blockDim.x) {
    int j = idx & 127;
    out[idx] = fmaf(t2[idx], sc[j], sh[j]);
  }
}

// vnsum[g] = vn[g] + sum_{i in graph g} h_in[i]   (batch sorted -> contiguous range)
__global__ void vnsum_kernel(const float* __restrict__ h_in, const int* __restrict__ gstart,
                             const float* __restrict__ vn, float* __restrict__ vnsum) {
  int g = blockIdx.x;
  int j = threadIdx.x;
  int s0 = gstart[g], s1 = gstart[g + 1];
  float acc = vn[g * EMB + j];
  for (int i = s0; i < s1; ++i) acc += h_in[i * EMB + j];
  vnsum[g * EMB + j] = acc;
}

// t_pre[i] = (1+eps)*h_in[i] + sum_{e: dst=i} relu(h16[src(e)] + edge_attr[e] @ eW + eb)
// Gathers from bf16 h16 (halves gather bytes); output pre-split bf16 hi/lo.
__global__ __launch_bounds__(128) void agg_kernel(
    const float* __restrict__ h_in, const ushort* __restrict__ h16,
    const int* __restrict__ row_start, const int2* __restrict__ el,
    const float* __restrict__ edge_attr, const float* __restrict__ eW,
    const float* __restrict__ eb, const float* __restrict__ eps_p, int l,
    ushort* __restrict__ tpre_h, ushort* __restrict__ tpre_l, int n) {
  __shared__ float W[10][EMB];
  __shared__ float bia[EMB];
  int j = threadIdx.x;  // 128
  #pragma unroll
  for (int k = 0; k < 10; ++k) W[k][j] = eW[k * EMB + j];
  bia[j] = eb[j];
  float epsv = 1.f + eps_p[l];
  __syncthreads();

  int i = blockIdx.x;
  int s0 = row_start[i], s1 = row_start[i + 1];
  float acc = epsv * h_in[(size_t)i * EMB + j];
  int p = s0;
  for (; p + 4 <= s1; p += 4) {
    int2 e0 = el[p], e1 = el[p + 1], e2 = el[p + 2], e3 = el[p + 3];
    float hv0 = bf2f(h16[(size_t)e0.y * EMB + j]);
    float hv1 = bf2f(h16[(size_t)e1.y * EMB + j]);
    float hv2 = bf2f(h16[(size_t)e2.y * EMB + j]);
    float hv3 = bf2f(h16[(size_t)e3.y * EMB + j]);
    const float* ea0 = edge_attr + (size_t)e0.x * 10;
    const float* ea1 = edge_attr + (size_t)e1.x * 10;
    const float* ea2 = edge_attr + (size_t)e2.x * 10;
    const float* ea3 = edge_attr + (size_t)e3.x * 10;
    float v0 = bia[j], v1 = bia[j], v2 = bia[j], v3 = bia[j];
    #pragma unroll
    for (int k = 0; k < 10; ++k) {
      float w = W[k][j];
      v0 = fmaf(ea0[k], w, v0);
      v1 = fmaf(ea1[k], w, v1);
      v2 = fmaf(ea2[k], w, v2);
      v3 = fmaf(ea3[k], w, v3);
    }
    acc += fmaxf(v0 + hv0, 0.f) + fmaxf(v1 + hv1, 0.f) +
           fmaxf(v2 + hv2, 0.f) + fmaxf(v3 + hv3, 0.f);
  }
  for (; p < s1; ++p) {
    int2 e0 = el[p];
    float hv0 = bf2f(h16[(size_t)e0.y * EMB + j]);
    const float* ea0 = edge_attr + (size_t)e0.x * 10;
    float v0 = bia[j];
    #pragma unroll
    for (int k = 0; k < 10; ++k) v0 = fmaf(ea0[k], W[k][j], v0);
    acc += fmaxf(v0 + hv0, 0.f);
  }
  // pre-split output (same numerics as gemm1's internal split)
  ushort hh = f2bf(acc);
  tpre_h[(size_t)i * EMB + j] = hh;
  tpre_l[(size_t)i * EMB + j] = f2bf(acc - bf2f(hh));
}

// ---------------- bf16x3 split-MFMA GEMM ----------------
// APRE: A supplied pre-split (Ath/Atl, bf16 hi/lo row-major [M][KT]) -> pure
// copy staging. Else A fp32 with optional BN+relu, split during staging.
template <int KT, int NT, bool BN_A, bool STATS, bool APRE>
__global__ __launch_bounds__(256) void gemm_mfma(
    const float* __restrict__ A, const ushort* __restrict__ Ath,
    const ushort* __restrict__ Atl,
    const ushort* __restrict__ Bth, const ushort* __restrict__ Btl,
    const float* __restrict__ bias,
    float* __restrict__ C, int M,
    const float* __restrict__ bnraw, const float* __restrict__ bng,
    const float* __restrict__ bnb, float* __restrict__ statraw) {
  constexpr int BM = 128, BN = 128, BK = 32;
  constexpr int LDK = BK + 8;
  constexpr int KSTEPS = KT / BK;
  __shared__ ushort Ah[BM][LDK], Al[BM][LDK];
  __shared__ ushort Bh[BN][LDK], Bl[BN][LDK];
  __shared__ float red[8][BN], redq[8][BN];
  constexpr int SCN = BN_A ? KT : 1;
  __shared__ float scS[SCN], shS[SCN];

  int tid = threadIdx.x;
  if (BN_A) {
    for (int k = tid; k < KT; k += 256) {
      float s = bnraw[k], q = bnraw[KT + k];
      float mean = s / (float)M;
      float var = q / (float)M - mean * mean;
      float scl = bng[k] * rsqrtf(var + BN_EPS);
      scS[k] = scl;
      shS[k] = bnb[k] - mean * scl;
    }
  }

  int wv = tid >> 6, lane = tid & 63;
  int wr = wv >> 1, wc = wv & 1;
  int lr = lane & 15, kg = lane >> 4;
  int bm0 = blockIdx.x * BM;
  int gc0 = blockIdx.y * BN;

  int sr = tid >> 1;
  int skq = (tid & 1) * 16;

  f32x4 acc[4][4];
  #pragma unroll
  for (int fm = 0; fm < 4; ++fm)
    #pragma unroll
    for (int fn = 0; fn < 4; ++fn) {
      float b = bias[gc0 + wc * 64 + fn * 16 + lr];
      acc[fm][fn][0] = b; acc[fm][fn][1] = b; acc[fm][fn][2] = b; acc[fm][fn][3] = b;
    }

  for (int kt = 0; kt < KSTEPS; ++kt) {
    __syncthreads();
    {
      int grow = bm0 + sr;
      if (APRE) {
        short8v z;
        #pragma unroll
        for (int q2 = 0; q2 < 8; ++q2) z[q2] = 0;
        if (grow < M) {
          const ushort* aph = Ath + (size_t)grow * KT + kt * BK + skq;
          const ushort* apl = Atl + (size_t)grow * KT + kt * BK + skq;
          *(short8v*)&Ah[sr][skq] = *(const short8v*)aph;
          *(short8v*)&Ah[sr][skq + 8] = *(const short8v*)(aph + 8);
          *(short8v*)&Al[sr][skq] = *(const short8v*)apl;
          *(short8v*)&Al[sr][skq + 8] = *(const short8v*)(apl + 8);
        } else {
          *(short8v*)&Ah[sr][skq] = z;
          *(short8v*)&Ah[sr][skq + 8] = z;
          *(short8v*)&Al[sr][skq] = z;
          *(short8v*)&Al[sr][skq + 8] = z;
        }
      } else {
        const float* ap = A + (size_t)grow * KT + kt * BK + skq;
        short8v ah0, al0, ah1, al1;
        #pragma unroll
        for (int u = 0; u < 4; ++u) {
          float4 v = (grow < M) ? *reinterpret_cast<const float4*>(ap + u * 4)
                                : make_float4(0.f, 0.f, 0.f, 0.f);
          if (BN_A) {
            int gk = kt * BK + skq + u * 4;
            v.x = fmaxf(fmaf(v.x, scS[gk + 0], shS[gk + 0]), 0.f);
            v.y = fmaxf(fmaf(v.y, scS[gk + 1], shS[gk + 1]), 0.f);
            v.z = fmaxf(fmaf(v.z, scS[gk + 2], shS[gk + 2]), 0.f);
            v.w = fmaxf(fmaf(v.w, scS[gk + 3], shS[gk + 3]), 0.f);
          }
          float vv0 = v.x, vv1 = v.y, vv2 = v.z, vv3 = v.w;
          ushort h0 = f2bf(vv0), h1 = f2bf(vv1), h2 = f2bf(vv2), h3 = f2bf(vv3);
          ushort w0 = f2bf(vv0 - bf2f(h0)), w1 = f2bf(vv1 - bf2f(h1));
          ushort w2 = f2bf(vv2 - bf2f(h2)), w3 = f2bf(vv3 - bf2f(h3));
          if (u < 2) {
            ah0[u * 4 + 0] = (short)h0; ah0[u * 4 + 1] = (short)h1;
            ah0[u * 4 + 2] = (short)h2; ah0[u * 4 + 3] = (short)h3;
            al0[u * 4 + 0] = (short)w0; al0[u * 4 + 1] = (short)w1;
            al0[u * 4 + 2] = (short)w2; al0[u * 4 + 3] = (short)w3;
          } else {
            ah1[(u - 2) * 4 + 0] = (short)h0; ah1[(u - 2) * 4 + 1] = (short)h1;
            ah1[(u - 2) * 4 + 2] = (short)h2; ah1[(u - 2) * 4 + 3] = (short)h3;
            al1[(u - 2) * 4 + 0] = (short)w0; al1[(u - 2) * 4 + 1] = (short)w1;
            al1[(u - 2) * 4 + 2] = (short)w2; al1[(u - 2) * 4 + 3] = (short)w3;
          }
        }
        *(short8v*)&Ah[sr][skq] = ah0;
        *(short8v*)&Ah[sr][skq + 8] = ah1;
        *(short8v*)&Al[sr][skq] = al0;
        *(short8v*)&Al[sr][skq + 8] = al1;
      }
    }
    {
      const ushort* bph = Bth + (size_t)(gc0 + sr) * KT + kt * BK + skq;
      const ushort* bpl = Btl + (size_t)(gc0 + sr) * KT + kt * BK + skq;
      *(short8v*)&Bh[sr][skq] = *(const short8v*)bph;
      *(short8v*)&Bh[sr][skq + 8] = *(const short8v*)(bph + 8);
      *(short8v*)&Bl[sr][skq] = *(const short8v*)bpl;
      *(short8v*)&Bl[sr][skq + 8] = *(const short8v*)(bpl + 8);
    }
    __syncthreads();
    short8v a_h[4], a_l[4], b_h[4], b_l[4];
    #pragma unroll
    for (int f = 0; f < 4; ++f) {
      a_h[f] = *(const short8v*)&Ah[wr * 64 + f * 16 + lr][kg * 8];
      a_l[f] = *(const short8v*)&Al[wr * 64 + f * 16 + lr][kg * 8];
      b_h[f] = *(const short8v*)&Bh[wc * 64 + f * 16 + lr][kg * 8];
      b_l[f] = *(const short8v*)&Bl[wc * 64 + f * 16 + lr][kg * 8];
    }
    #pragma unroll
    for (int fm = 0; fm < 4; ++fm)
      #pragma unroll
      for (int fn = 0; fn < 4; ++fn) {
        acc[fm][fn] = __builtin_amdgcn_mfma_f32_16x16x32_bf16(a_h[fm], b_h[fn], acc[fm][fn], 0, 0, 0);
        acc[fm][fn] = __builtin_amdgcn_mfma_f32_16x16x32_bf16(a_h[fm], b_l[fn], acc[fm][fn], 0, 0, 0);
        acc[fm][fn] = __builtin_amdgcn_mfma_f32_16x16x32_bf16(a_l[fm], b_h[fn], acc[fm][fn], 0, 0, 0);
      }
  }

  #pragma unroll
  for (int fm = 0; fm < 4; ++fm) {
    int rb = bm0 + wr * 64 + fm * 16 + kg * 4;
    #pragma unroll
    for (int i = 0; i < 4; ++i) {
      int grow = rb + i;
      if (grow < M) {
        float* cp = C + (size_t)grow * NT + gc0 + wc * 64 + lr;
        #pragma unroll
        for (int fn = 0; fn < 4; ++fn) cp[fn * 16] = acc[fm][fn][i];
      }
    }
  }

  if (STATS) {
    #pragma unroll
    for (int fn = 0; fn < 4; ++fn) {
      float s = 0.f, q = 0.f;
      #pragma unroll
      for (int fm = 0; fm < 4; ++fm) {
        int rb = bm0 + wr * 64 + fm * 16 + kg * 4;
        #pragma unroll
        for (int i = 0; i < 4; ++i) {
          if (rb + i < M) {
            float v = acc[fm][fn][i];
            s += v;
            q = fmaf(v, v, q);
          }
        }
      }
      red[wr * 4 + kg][wc * 64 + fn * 16 + lr] = s;
      redq[wr * 4 + kg][wc * 64 + fn * 16 + lr] = q;
    }
    __syncthreads();
    if (tid < BN) {
      float s = 0.f, q = 0.f;
      #pragma unroll
      for (int r2 = 0; r2 < 8; ++r2) {
        s += red[r2][tid];
        q += redq[r2][tid];
      }
      int gcol = gc0 + tid;
      atomicAdd(&statraw[gcol], s);
      atomicAdd(&statraw[NT + gcol], q);
    }
  }
}

// ---------------- virtual-node MLP (tiny: 512 rows) ----------------

__global__ void vmlp1_kernel(const float* __restrict__ vtmp, const float* __restrict__ W,
                             const float* __restrict__ b, float* __restrict__ u1,
                             float* __restrict__ vs1raw) {
  __shared__ float a[EMB];
  int g = blockIdx.x;
  int j = threadIdx.x;  // 256
  if (j < EMB) a[j] = vtmp[g * EMB + j];
  __syncthreads();
  float acc = b[j];
  #pragma unroll 8
  for (int k = 0; k < EMB; ++k) acc = fmaf(a[k], W[k * 256 + j], acc);
  u1[g * 256 + j] = acc;
  atomicAdd(&vs1raw[j], acc);
  atomicAdd(&vs1raw[256 + j], acc * acc);
}

__global__ void vmlp2_kernel(const float* __restrict__ u1, const float* __restrict__ vs1raw,
                             const float* __restrict__ g1, const float* __restrict__ b1,
                             const float* __restrict__ W, const float* __restrict__ b2,
                             float* __restrict__ u2, float* __restrict__ vs2raw) {
  __shared__ float a[256];
  __shared__ float sc[256], sh[256];
  int g = blockIdx.x;
  int j = threadIdx.x;  // 128
  for (int k = j; k < 256; k += EMB) {
    float s = vs1raw[k], q = vs1raw[256 + k];
    float mean = s / (float)NGR;
    float var = q / (float)NGR - mean * mean;
    float scl = g1[k] * rsqrtf(var + BN_EPS);
    sc[k] = scl;
    sh[k] = b1[k] - mean * scl;
  }
  __syncthreads();
  for (int k = j; k < 256; k += EMB)
    a[k] = fmaxf(fmaf(u1[g * 256 + k], sc[k], sh[k]), 0.f);
  __syncthreads();
  float acc = b2[j];
  #pragma unroll 8
  for (int k = 0; k < 256; ++k) acc = fmaf(a[k], W[k * EMB + j], acc);
  u2[g * EMB + j] = acc;
  atomicAdd(&vs2raw[j], acc);
  atomicAdd(&vs2raw[EMB + j], acc * acc);
}

__global__ void vnupd_kernel(const float* __restrict__ u2, const float* __restrict__ vs2raw,
                             const float* __restrict__ g2, const float* __restrict__ b2,
                             float* __restrict__ vn) {
  __shared__ float sc[EMB], sh[EMB];
  int g = blockIdx.x;
  int j = threadIdx.x;  // 128
  {
    float s = vs2raw[j], q = vs2raw[EMB + j];
    float mean = s / (float)NGR;
    float var = q / (float)NGR - mean * mean;
    float scl = g2[j] * rsqrtf(var + BN_EPS);
    sc[j] = scl;
    sh[j] = b2[j] - mean * scl;
  }
  __syncthreads();
  vn[g * EMB + j] = fmaxf(fmaf(u2[g * EMB + j], sc[j], sh[j]), 0.f);
}

// ---------------- host launcher ----------------

extern "C" void kernel_launch(void* const* d_in, const int* in_sizes, int n_in,
                              void* d_out, int out_size, void* d_ws, size_t ws_size,
                              hipStream_t stream) {
  const float* x        = (const float*)d_in[0];
  const int*   ei       = (const int*)d_in[1];
  const float* eattr    = (const float*)d_in[2];
  const int*   batch    = (const int*)d_in[3];
  const float* node_W   = (const float*)d_in[4];
  const float* node_b   = (const float*)d_in[5];
  const float* vn_emb   = (const float*)d_in[6];
  const float* eps      = (const float*)d_in[7];
  const float* edge_W   = (const float*)d_in[8];
  const float* edge_b   = (const float*)d_in[9];
  const float* conv_W1  = (const float*)d_in[10];
  const float* conv_b1  = (const float*)d_in[11];
  const float* cbn_g    = (const float*)d_in[12];
  const float* cbn_b    = (const float*)d_in[13];
  const float* conv_W2  = (const float*)d_in[14];
  const float* conv_b2  = (const float*)d_in[15];
  const float* bn_g     = (const float*)d_in[16];
  const float* bn_b     = (const float*)d_in[17];
  const float* vW1      = (const float*)d_in[18];
  const float* vb1      = (const float*)d_in[19];
  const float* vbn1_g   = (const float*)d_in[20];
  const float* vbn1_b   = (const float*)d_in[21];
  const float* vW2      = (const float*)d_in[22];
  const float* vb2      = (const float*)d_in[23];
  const float* vbn2_g   = (const float*)d_in[24];
  const float* vbn2_b   = (const float*)d_in[25];

  const int n = in_sizes[0] / 9;   // 50000
  const int E = in_sizes[1] / 2;   // 600000
  const int nb = (n + 2047) / 2048;

  // -------- workspace carve (aligned 256B) --------
  char* p = (char*)d_ws;
  auto carve = [&](size_t bytes) {
    char* r = p;
    p += (bytes + 255) & ~(size_t)255;
    return r;
  };
  float* h_in   = (float*)carve((size_t)n * EMB * 4);
  ushort* h16   = (ushort*)carve((size_t)n * EMB * 2);
  float* t1     = (float*)carve((size_t)n * 256 * 4);
  float* t2     = (float*)carve((size_t)n * EMB * 4);
  ushort* tpre_h = (ushort*)carve((size_t)n * EMB * 2);
  ushort* tpre_l = (ushort*)carve((size_t)n * EMB * 2);
  float* vn     = (float*)carve((size_t)NGR * EMB * 4);
  float* vnsum  = (float*)carve((size_t)NGR * EMB * 4);
  float* u1     = (float*)carve((size_t)NGR * 256 * 4);
  float* u2     = (float*)carve((size_t)NGR * EMB * 4);
  float* stats  = (float*)carve((size_t)NLAYER * 1536 * 4);
  int* deg      = (int*)carve((size_t)n * 4);
  int* rstart   = (int*)carve((size_t)(n + 1) * 4);
  int* cursor   = (int*)carve((size_t)n * 4);
  int2* el      = (int2*)carve((size_t)E * 8);
  int* gstart   = (int*)carve((size_t)(NGR + 1) * 4);
  int* bsum     = (int*)carve((size_t)64 * 4);
  int* boff     = (int*)carve((size_t)64 * 4);
  ushort* wt1h  = (ushort*)carve((size_t)NLAYER * 256 * 128 * 2);
  ushort* wt1l  = (ushort*)carve((size_t)NLAYER * 256 * 128 * 2);
  ushort* wt2h  = (ushort*)carve((size_t)NLAYER * 128 * 256 * 2);
  ushort* wt2l  = (ushort*)carve((size_t)NLAYER * 128 * 256 * 2);
  float* h0     = t1;  // alias: h0 consumed (by l=0 hin) before t1 written

  auto s1  = [&](int l) { return stats + (size_t)l * 1536; };
  auto s2  = [&](int l) { return stats + (size_t)l * 1536 + 512; };
  auto vs1 = [&](int l) { return stats + (size_t)l * 1536 + 768; };
  auto vs2 = [&](int l) { return stats + (size_t)l * 1536 + 1280; };

  // -------- setup --------
  init_kernel<<<(NGR * EMB + 255) / 256, 256, 0, stream>>>(deg, n, stats, NLAYER * 1536, vn, vn_emb);
  deg_kernel<<<(E + 255) / 256, 256, 0, stream>>>(ei, deg, E);
  scan1_kernel<<<nb, 256, 0, stream>>>(deg, bsum, n);
  scan2_kernel<<<1, 64, 0, stream>>>(bsum, boff, rstart + n, nb);
  scan3_kernel<<<nb, 256, 0, stream>>>(deg, boff, rstart, cursor, n);
  fill_kernel<<<(E + 255) / 256, 256, 0, stream>>>(ei, cursor, el, E);
  bounds_kernel<<<(NGR + 1 + 255) / 256, 256, 0, stream>>>(batch, gstart, n, NGR);
  {
    int tot1 = NLAYER * 128 * 256;   // conv_W1: K=128, N=256
    wtrans_kernel<<<(tot1 + 255) / 256, 256, 0, stream>>>(conv_W1, wt1h, wt1l, 128, 256, tot1);
    int tot2 = NLAYER * 256 * 128;   // conv_W2: K=256, N=128
    wtrans_kernel<<<(tot2 + 255) / 256, 256, 0, stream>>>(conv_W2, wt2h, wt2l, 256, 128, tot2);
  }
  encoder_kernel<<<2048, 256, 0, stream>>>(x, node_W, node_b, h0, n);

  const int mtiles = (n + 127) / 128;

  for (int l = 0; l < NLAYER; ++l) {
    if (l == 0)
      hin_kernel<true><<<4096, 256, 0, stream>>>(h0, vn, batch, nullptr, nullptr, nullptr,
                                                 h_in, h16, n);
    else
      hin_kernel<false><<<4096, 256, 0, stream>>>(t2, vn, batch, s2(l - 1),
                                                  bn_g + (size_t)(l - 1) * EMB,
                                                  bn_b + (size_t)(l - 1) * EMB, h_in, h16, n);
    if (l < NLAYER - 1)
      vnsum_kernel<<<NGR, EMB, 0, stream>>>(h_in, gstart, vn, vnsum);

    agg_kernel<<<n, EMB, 0, stream>>>(h_in, h16, rstart, el, eattr,
                                      edge_W + (size_t)l * 10 * EMB,
                                      edge_b + (size_t)l * EMB, eps, l, tpre_h, tpre_l, n);

    gemm_mfma<128, 256, false, true, true><<<dim3(mtiles, 2), 256, 0, stream>>>(
        nullptr, tpre_h, tpre_l, wt1h + (size_t)l * 256 * 128, wt1l + (size_t)l * 256 * 128,
        conv_b1 + (size_t)l * 256, t1, n, nullptr, nullptr, nullptr, s1(l));

    gemm_mfma<256, 128, true, true, false><<<dim3(mtiles, 1), 256, 0, stream>>>(
        t1, nullptr, nullptr, wt2h + (size_t)l * 128 * 256, wt2l + (size_t)l * 128 * 256,
        conv_b2 + (size_t)l * 128, t2, n,
        s1(l), cbn_g + (size_t)l * 256, cbn_b + (size_t)l * 256, s2(l));

    if (l < NLAYER - 1) {
      vmlp1_kernel<<<NGR, 256, 0, stream>>>(vnsum, vW1 + (size_t)l * 128 * 256,
                                            vb1 + (size_t)l * 256, u1, vs1(l));
      vmlp2_kernel<<<NGR, EMB, 0, stream>>>(u1, vs1(l), vbn1_g + (size_t)l * 256,
                                            vbn1_b + (size_t)l * 256,
                                            vW2 + (size_t)l * 256 * 128,
                                            vb2 + (size_t)l * EMB, u2, vs2(l));
      vnupd_kernel<<<NGR, EMB, 0, stream>>>(u2, vs2(l), vbn2_g + (size_t)l * EMB,
                                            vbn2_b + (size_t)l * EMB, vn);
    }
  }

  out_kernel<<<4096, 256, 0, stream>>>(t2, s2(NLAYER - 1),
                                       bn_g + (size_t)(NLAYER - 1) * EMB,
                                       bn_b + (size_t)(NLAYER - 1) * EMB,
                                       (float*)d_out, n);
}

// Round 10
// 1270.843 us; speedup vs baseline: 1.0076x; 1.0076x over previous
//
#include <hip/hip_runtime.h>

// GIN + virtual-node GNN, 5 layers.
// R10: (a) packed edge records {src, bf16 edge_attr[10]} in CSR order (32B,
//      built once in fill) -> agg reads one sequential stream per edge; kills
//      edge_attr's ~77MB over-fetch (40B rows -> 2 lines) + one dependent-load
//      level. (b) agg edge loop 8-wide (more outstanding L3 gathers; topology
//      is uniformly random -> no locality exists, latency hiding is the only
//      lever). Rest unchanged from R9.

#define EMB 128
#define NGR 512
#define NLAYER 5
static constexpr float BN_EPS = 1e-5f;

typedef __attribute__((ext_vector_type(8))) short short8v;  // 8 bf16 = 4 VGPR
typedef __attribute__((ext_vector_type(4))) float f32x4;

__device__ __forceinline__ ushort f2bf(float f) {
  union { float f; unsigned u; } c; c.f = f;
  return (ushort)((c.u + 0x7FFFu + ((c.u >> 16) & 1u)) >> 16);
}
__device__ __forceinline__ float bf2f(ushort h) {
  union { unsigned u; float f; } c; c.u = ((unsigned)h) << 16;
  return c.f;
}

// 32B packed edge record: src node + bf16 edge features (layer-independent)
struct __attribute__((aligned(32))) EPack {
  int src;
  ushort ea[10];
  ushort pad[3];
};

// ---------------- setup kernels ----------------

__global__ void init_kernel(int* __restrict__ deg, int ndeg,
                            float* __restrict__ stats, int nstats,
                            float* __restrict__ vn, const float* __restrict__ vn_emb) {
  int idx = blockIdx.x * blockDim.x + threadIdx.x;
  if (idx < ndeg) deg[idx] = 0;
  if (idx < nstats) stats[idx] = 0.f;
  if (idx < NGR * EMB) vn[idx] = vn_emb[idx & (EMB - 1)];
}

__global__ void deg_kernel(const int* __restrict__ ei, int* __restrict__ deg, int E) {
  int e = blockIdx.x * blockDim.x + threadIdx.x;
  if (e < E) atomicAdd(&deg[ei[E + e]], 1);
}

// ---- hierarchical prefix scan over deg[n] (2048 elems per 256-thr block) ----

__global__ void scan1_kernel(const int* __restrict__ deg, int* __restrict__ bsum, int n) {
  __shared__ int ws[4];
  int t = threadIdx.x;
  int base = blockIdx.x * 2048 + t * 8;
  int s = 0;
  #pragma unroll
  for (int i = 0; i < 8; ++i) {
    int idx = base + i;
    if (idx < n) s += deg[idx];
  }
  #pragma unroll
  for (int off = 32; off; off >>= 1) s += __shfl_down(s, off);
  if ((t & 63) == 0) ws[t >> 6] = s;
  __syncthreads();
  if (t == 0) bsum[blockIdx.x] = ws[0] + ws[1] + ws[2] + ws[3];
}

// single 64-thread block; nb <= 64. boff = exclusive scan; *row_n = total.
__global__ void scan2_kernel(const int* __restrict__ bsum, int* __restrict__ boff,
                             int* __restrict__ row_n, int nb) {
  int t = threadIdx.x;
  int mine = (t < nb) ? bsum[t] : 0;
  int v = mine;
  #pragma unroll
  for (int off = 1; off < 64; off <<= 1) {
    int u = __shfl_up(v, off);
    if (t >= off) v += u;
  }
  if (t < nb) boff[t] = v - mine;
  if (t == nb - 1) *row_n = v;
}

__global__ __launch_bounds__(256) void scan3_kernel(const int* __restrict__ deg,
                                                    const int* __restrict__ boff,
                                                    int* __restrict__ row_start,
                                                    int* __restrict__ cursor, int n) {
  __shared__ int lsum[256];
  int t = threadIdx.x;
  int base = blockIdx.x * 2048 + t * 8;
  int loc[8];
  int s = 0;
  #pragma unroll
  for (int i = 0; i < 8; ++i) {
    int idx = base + i;
    int d = (idx < n) ? deg[idx] : 0;
    loc[i] = s;
    s += d;
  }
  lsum[t] = s;
  __syncthreads();
  #pragma unroll
  for (int off = 1; off < 256; off <<= 1) {
    int v2 = (t >= off) ? lsum[t - off] : 0;
    __syncthreads();
    lsum[t] += v2;
    __syncthreads();
  }
  int toff = boff[blockIdx.x] + lsum[t] - s;  // exclusive across grid
  #pragma unroll
  for (int i = 0; i < 8; ++i) {
    int idx = base + i;
    if (idx < n) {
      int rs = toff + loc[i];
      row_start[idx] = rs;
      cursor[idx] = rs;
    }
  }
}

// pack {src, bf16 edge_attr} into CSR position (once; reused all 5 layers)
__global__ void fill_kernel(const int* __restrict__ ei, int* __restrict__ cursor,
                            const float* __restrict__ eattr,
                            EPack* __restrict__ epk, int E) {
  int e = blockIdx.x * blockDim.x + threadIdx.x;
  if (e < E) {
    int d = ei[E + e];
    int pos = atomicAdd(&cursor[d], 1);
    EPack r;
    r.src = ei[e];
    const float* ea = eattr + (size_t)e * 10;
    #pragma unroll
    for (int k = 0; k < 10; ++k) r.ea[k] = f2bf(ea[k]);
    r.pad[0] = r.pad[1] = r.pad[2] = 0;
    epk[pos] = r;
  }
}

// graph_start[g] = lower_bound(batch, g); batch is sorted. Handles empty graphs.
__global__ void bounds_kernel(const int* __restrict__ batch, int* __restrict__ gstart,
                              int n, int ng) {
  int g = blockIdx.x * blockDim.x + threadIdx.x;
  if (g > ng) return;
  int lo = 0, hi = n;
  while (lo < hi) {
    int mid = (lo + hi) >> 1;
    if (batch[mid] < g) lo = mid + 1; else hi = mid;
  }
  gstart[g] = lo;
}

// W [L][K][N] -> Wth/Wtl [L][N][K] (transpose + bf16 hi/lo split), per flat idx
__global__ void wtrans_kernel(const float* __restrict__ W, ushort* __restrict__ Wth,
                              ushort* __restrict__ Wtl, int K, int N, int total) {
  int idx = blockIdx.x * blockDim.x + threadIdx.x;
  if (idx >= total) return;
  int kk = idx % K;
  int t = idx / K;
  int nn = t % N;
  int l = t / N;
  float v = W[((size_t)l * K + kk) * N + nn];
  ushort h = f2bf(v);
  Wth[idx] = h;
  Wtl[idx] = f2bf(v - bf2f(h));
}

// h0 = x @ node_W + node_b   (K=9, N=128)
__global__ void encoder_kernel(const float* __restrict__ x, const float* __restrict__ W,
                               const float* __restrict__ b, float* __restrict__ h0, int n) {
  __shared__ float Ws[9][EMB];
  __shared__ float bs[EMB];
  int t = threadIdx.x;
  if (t < EMB) {
    #pragma unroll
    for (int k = 0; k < 9; ++k) Ws[k][t] = W[k * EMB + t];
    bs[t] = b[t];
  }
  __syncthreads();
  int total = n * EMB;
  for (int idx = blockIdx.x * blockDim.x + t; idx < total; idx += gridDim.x * blockDim.x) {
    int i = idx >> 7, j = idx & 127;
    const float* xr = x + i * 9;
    float acc = bs[j];
    #pragma unroll
    for (int k = 0; k < 9; ++k) acc = fmaf(xr[k], Ws[k][j], acc);
    h0[idx] = acc;
  }
}

// ---------------- per-layer kernels ----------------

// h_in = (RAW ? src : relu(bn2(src))) + vn[batch]; also writes bf16 copy h16
template <bool RAW>
__global__ void hin_kernel(const float* __restrict__ src, const float* __restrict__ vn,
                           const int* __restrict__ batch, const float* __restrict__ s2raw,
                           const float* __restrict__ g2, const float* __restrict__ b2,
                           float* __restrict__ h_in, ushort* __restrict__ h16, int n) {
  __shared__ float sc[EMB], sh[EMB];
  if (!RAW) {
    int j = threadIdx.x;
    if (j < EMB) {
      float s = s2raw[j], q = s2raw[EMB + j];
      float mean = s / (float)n;
      float var = q / (float)n - mean * mean;
      float scl = g2[j] * rsqrtf(var + BN_EPS);
      sc[j] = scl;
      sh[j] = b2[j] - mean * scl;
    }
    __syncthreads();
  }
  int total = n * EMB;
  for (int idx = blockIdx.x * blockDim.x + threadIdx.x; idx < total; idx += gridDim.x * blockDim.x) {
    int i = idx >> 7, j = idx & 127;
    float v = src[idx];
    if (!RAW) v = fmaxf(fmaf(v, sc[j], sh[j]), 0.f);
    float hv = v + vn[batch[i] * EMB + j];
    h_in[idx] = hv;
    h16[idx] = f2bf(hv);
  }
}

// final output: d_out = bn2(t2)  (no relu, layer L-1)
__global__ void out_kernel(const float* __restrict__ t2, const float* __restrict__ s2raw,
                           const float* __restrict__ g2, const float* __restrict__ b2,
                           float* __restrict__ out, int n) {
  __shared__ float sc[EMB], sh[EMB];
  int j0 = threadIdx.x;
  if (j0 < EMB) {
    float s = s2raw[j0], q = s2raw[EMB + j0];
    float mean = s / (float)n;
    float var = q / (float)n - mean * mean;
    float scl = g2[j0] * rsqrtf(var + BN_EPS);
    sc[j0] = scl;
    sh[j0] = b2[j0] - mean * scl;
  }
  __syncthreads();
  int total = n * EMB;
  for (int idx = blockIdx.x * blockDim.x + threadIdx.x; idx < total; idx += gridDim.x * blockDim.x) {
    int j = idx & 127;
    out[idx] = fmaf(t2[idx], sc[j], sh[j]);
  }
}

// vnsum[g] = vn[g] + sum_{i in graph g} h_in[i]   (batch sorted -> contiguous range)
__global__ void vnsum_kernel(const float* __restrict__ h_in, const int* __restrict__ gstart,
                             const float* __restrict__ vn, float* __restrict__ vnsum) {
  int g = blockIdx.x;
  int j = threadIdx.x;
  int s0 = gstart[g], s1 = gstart[g + 1];
  float acc = vn[g * EMB + j];
  for (int i = s0; i < s1; ++i) acc += h_in[i * EMB + j];
  vnsum[g * EMB + j] = acc;
}

// t_pre[i] = (1+eps)*h_in[i] + sum_{e: dst=i} relu(h16[src(e)] + ea(e) @ eW + eb)
// Packed sequential edge stream + random h16 gathers; 8/4/1-wide unroll.
__global__ __launch_bounds__(128) void agg_kernel(
    const float* __restrict__ h_in, const ushort* __restrict__ h16,
    const int* __restrict__ row_start, const EPack* __restrict__ epk,
    const float* __restrict__ eW, const float* __restrict__ eb,
    const float* __restrict__ eps_p, int l,
    ushort* __restrict__ tpre_h, ushort* __restrict__ tpre_l, int n) {
  __shared__ float W[10][EMB];
  __shared__ float bia[EMB];
  int j = threadIdx.x;  // 128
  #pragma unroll
  for (int k = 0; k < 10; ++k) W[k][j] = eW[k * EMB + j];
  bia[j] = eb[j];
  float epsv = 1.f + eps_p[l];
  __syncthreads();

  int i = blockIdx.x;
  int s0 = row_start[i], s1 = row_start[i + 1];
  float acc = epsv * h_in[(size_t)i * EMB + j];
  int p = s0;
  for (; p + 8 <= s1; p += 8) {
    int srcs[8];
    #pragma unroll
    for (int u = 0; u < 8; ++u) srcs[u] = epk[p + u].src;
    float hv[8];
    #pragma unroll
    for (int u = 0; u < 8; ++u) hv[u] = bf2f(h16[(size_t)srcs[u] * EMB + j]);
    #pragma unroll
    for (int u = 0; u < 8; ++u) {
      const EPack* ep = epk + p + u;
      float v = bia[j];
      #pragma unroll
      for (int k = 0; k < 10; ++k) v = fmaf(bf2f(ep->ea[k]), W[k][j], v);
      acc += fmaxf(v + hv[u], 0.f);
    }
  }
  for (; p + 4 <= s1; p += 4) {
    int srcs[4];
    #pragma unroll
    for (int u = 0; u < 4; ++u) srcs[u] = epk[p + u].src;
    float hv[4];
    #pragma unroll
    for (int u = 0; u < 4; ++u) hv[u] = bf2f(h16[(size_t)srcs[u] * EMB + j]);
    #pragma unroll
    for (int u = 0; u < 4; ++u) {
      const EPack* ep = epk + p + u;
      float v = bia[j];
      #pragma unroll
      for (int k = 0; k < 10; ++k) v = fmaf(bf2f(ep->ea[k]), W[k][j], v);
      acc += fmaxf(v + hv[u], 0.f);
    }
  }
  for (; p < s1; ++p) {
    const EPack* ep = epk + p;
    float hv0 = bf2f(h16[(size_t)ep->src * EMB + j]);
    float v = bia[j];
    #pragma unroll
    for (int k = 0; k < 10; ++k) v = fmaf(bf2f(ep->ea[k]), W[k][j], v);
    acc += fmaxf(v + hv0, 0.f);
  }
  // pre-split output (same numerics as gemm1's internal split)
  ushort hh = f2bf(acc);
  tpre_h[(size_t)i * EMB + j] = hh;
  tpre_l[(size_t)i * EMB + j] = f2bf(acc - bf2f(hh));
}

// ---------------- bf16x3 split-MFMA GEMM ----------------
// APRE: A supplied pre-split (Ath/Atl, bf16 hi/lo row-major [M][KT]) -> pure
// copy staging. Else A fp32 with optional BN+relu, split during staging.
template <int KT, int NT, bool BN_A, bool STATS, bool APRE>
__global__ __launch_bounds__(256) void gemm_mfma(
    const float* __restrict__ A, const ushort* __restrict__ Ath,
    const ushort* __restrict__ Atl,
    const ushort* __restrict__ Bth, const ushort* __restrict__ Btl,
    const float* __restrict__ bias,
    float* __restrict__ C, int M,
    const float* __restrict__ bnraw, const float* __restrict__ bng,
    const float* __restrict__ bnb, float* __restrict__ statraw) {
  constexpr int BM = 128, BN = 128, BK = 32;
  constexpr int LDK = BK + 8;
  constexpr int KSTEPS = KT / BK;
  __shared__ ushort Ah[BM][LDK], Al[BM][LDK];
  __shared__ ushort Bh[BN][LDK], Bl[BN][LDK];
  __shared__ float red[8][BN], redq[8][BN];
  constexpr int SCN = BN_A ? KT : 1;
  __shared__ float scS[SCN], shS[SCN];

  int tid = threadIdx.x;
  if (BN_A) {
    for (int k = tid; k < KT; k += 256) {
      float s = bnraw[k], q = bnraw[KT + k];
      float mean = s / (float)M;
      float var = q / (float)M - mean * mean;
      float scl = bng[k] * rsqrtf(var + BN_EPS);
      scS[k] = scl;
      shS[k] = bnb[k] - mean * scl;
    }
  }

  int wv = tid >> 6, lane = tid & 63;
  int wr = wv >> 1, wc = wv & 1;
  int lr = lane & 15, kg = lane >> 4;
  int bm0 = blockIdx.x * BM;
  int gc0 = blockIdx.y * BN;

  int sr = tid >> 1;
  int skq = (tid & 1) * 16;

  f32x4 acc[4][4];
  #pragma unroll
  for (int fm = 0; fm < 4; ++fm)
    #pragma unroll
    for (int fn = 0; fn < 4; ++fn) {
      float b = bias[gc0 + wc * 64 + fn * 16 + lr];
      acc[fm][fn][0] = b; acc[fm][fn][1] = b; acc[fm][fn][2] = b; acc[fm][fn][3] = b;
    }

  for (int kt = 0; kt < KSTEPS; ++kt) {
    __syncthreads();
    {
      int grow = bm0 + sr;
      if (APRE) {
        short8v z;
        #pragma unroll
        for (int q2 = 0; q2 < 8; ++q2) z[q2] = 0;
        if (grow < M) {
          const ushort* aph = Ath + (size_t)grow * KT + kt * BK + skq;
          const ushort* apl = Atl + (size_t)grow * KT + kt * BK + skq;
          *(short8v*)&Ah[sr][skq] = *(const short8v*)aph;
          *(short8v*)&Ah[sr][skq + 8] = *(const short8v*)(aph + 8);
          *(short8v*)&Al[sr][skq] = *(const short8v*)apl;
          *(short8v*)&Al[sr][skq + 8] = *(const short8v*)(apl + 8);
        } else {
          *(short8v*)&Ah[sr][skq] = z;
          *(short8v*)&Ah[sr][skq + 8] = z;
          *(short8v*)&Al[sr][skq] = z;
          *(short8v*)&Al[sr][skq + 8] = z;
        }
      } else {
        const float* ap = A + (size_t)grow * KT + kt * BK + skq;
        short8v ah0, al0, ah1, al1;
        #pragma unroll
        for (int u = 0; u < 4; ++u) {
          float4 v = (grow < M) ? *reinterpret_cast<const float4*>(ap + u * 4)
                                : make_float4(0.f, 0.f, 0.f, 0.f);
          if (BN_A) {
            int gk = kt * BK + skq + u * 4;
            v.x = fmaxf(fmaf(v.x, scS[gk + 0], shS[gk + 0]), 0.f);
            v.y = fmaxf(fmaf(v.y, scS[gk + 1], shS[gk + 1]), 0.f);
            v.z = fmaxf(fmaf(v.z, scS[gk + 2], shS[gk + 2]), 0.f);
            v.w = fmaxf(fmaf(v.w, scS[gk + 3], shS[gk + 3]), 0.f);
          }
          float vv0 = v.x, vv1 = v.y, vv2 = v.z, vv3 = v.w;
          ushort h0 = f2bf(vv0), h1 = f2bf(vv1), h2 = f2bf(vv2), h3 = f2bf(vv3);
          ushort w0 = f2bf(vv0 - bf2f(h0)), w1 = f2bf(vv1 - bf2f(h1));
          ushort w2 = f2bf(vv2 - bf2f(h2)), w3 = f2bf(vv3 - bf2f(h3));
          if (u < 2) {
            ah0[u * 4 + 0] = (short)h0; ah0[u * 4 + 1] = (short)h1;
            ah0[u * 4 + 2] = (short)h2; ah0[u * 4 + 3] = (short)h3;
            al0[u * 4 + 0] = (short)w0; al0[u * 4 + 1] = (short)w1;
            al0[u * 4 + 2] = (short)w2; al0[u * 4 + 3] = (short)w3;
          } else {
            ah1[(u - 2) * 4 + 0] = (short)h0; ah1[(u - 2) * 4 + 1] = (short)h1;
            ah1[(u - 2) * 4 + 2] = (short)h2; ah1[(u - 2) * 4 + 3] = (short)h3;
            al1[(u - 2) * 4 + 0] = (short)w0; al1[(u - 2) * 4 + 1] = (short)w1;
            al1[(u - 2) * 4 + 2] = (short)w2; al1[(u - 2) * 4 + 3] = (short)w3;
          }
        }
        *(short8v*)&Ah[sr][skq] = ah0;
        *(short8v*)&Ah[sr][skq + 8] = ah1;
        *(short8v*)&Al[sr][skq] = al0;
        *(short8v*)&Al[sr][skq + 8] = al1;
      }
    }
    {
      const ushort* bph = Bth + (size_t)(gc0 + sr) * KT + kt * BK + skq;
      const ushort* bpl = Btl + (size_t)(gc0 + sr) * KT + kt * BK + skq;
      *(short8v*)&Bh[sr][skq] = *(const short8v*)bph;
      *(short8v*)&Bh[sr][skq + 8] = *(const short8v*)(bph + 8);
      *(short8v*)&Bl[sr][skq] = *(const short8v*)bpl;
      *(short8v*)&Bl[sr][skq + 8] = *(const short8v*)(bpl + 8);
    }
    __syncthreads();
    short8v a_h[4], a_l[4], b_h[4], b_l[4];
    #pragma unroll
    for (int f = 0; f < 4; ++f) {
      a_h[f] = *(const short8v*)&Ah[wr * 64 + f * 16 + lr][kg * 8];
      a_l[f] = *(const short8v*)&Al[wr * 64 + f * 16 + lr][kg * 8];
      b_h[f] = *(const short8v*)&Bh[wc * 64 + f * 16 + lr][kg * 8];
      b_l[f] = *(const short8v*)&Bl[wc * 64 + f * 16 + lr][kg * 8];
    }
    #pragma unroll
    for (int fm = 0; fm < 4; ++fm)
      #pragma unroll
      for (int fn = 0; fn < 4; ++fn) {
        acc[fm][fn] = __builtin_amdgcn_mfma_f32_16x16x32_bf16(a_h[fm], b_h[fn], acc[fm][fn], 0, 0, 0);
        acc[fm][fn] = __builtin_amdgcn_mfma_f32_16x16x32_bf16(a_h[fm], b_l[fn], acc[fm][fn], 0, 0, 0);
        acc[fm][fn] = __builtin_amdgcn_mfma_f32_16x16x32_bf16(a_l[fm], b_h[fn], acc[fm][fn], 0, 0, 0);
      }
  }

  #pragma unroll
  for (int fm = 0; fm < 4; ++fm) {
    int rb = bm0 + wr * 64 + fm * 16 + kg * 4;
    #pragma unroll
    for (int i = 0; i < 4; ++i) {
      int grow = rb + i;
      if (grow < M) {
        float* cp = C + (size_t)grow * NT + gc0 + wc * 64 + lr;
        #pragma unroll
        for (int fn = 0; fn < 4; ++fn) cp[fn * 16] = acc[fm][fn][i];
      }
    }
  }

  if (STATS) {
    #pragma unroll
    for (int fn = 0; fn < 4; ++fn) {
      float s = 0.f, q = 0.f;
      #pragma unroll
      for (int fm = 0; fm < 4; ++fm) {
        int rb = bm0 + wr * 64 + fm * 16 + kg * 4;
        #pragma unroll
        for (int i = 0; i < 4; ++i) {
          if (rb + i < M) {
            float v = acc[fm][fn][i];
            s += v;
            q = fmaf(v, v, q);
          }
        }
      }
      red[wr * 4 + kg][wc * 64 + fn * 16 + lr] = s;
      redq[wr * 4 + kg][wc * 64 + fn * 16 + lr] = q;
    }
    __syncthreads();
    if (tid < BN) {
      float s = 0.f, q = 0.f;
      #pragma unroll
      for (int r2 = 0; r2 < 8; ++r2) {
        s += red[r2][tid];
        q += redq[r2][tid];
      }
      int gcol = gc0 + tid;
      atomicAdd(&statraw[gcol], s);
      atomicAdd(&statraw[NT + gcol], q);
    }
  }
}

// ---------------- virtual-node MLP (tiny: 512 rows) ----------------

__global__ void vmlp1_kernel(const float* __restrict__ vtmp, const float* __restrict__ W,
                             const float* __restrict__ b, float* __restrict__ u1,
                             float* __restrict__ vs1raw) {
  __shared__ float a[EMB];
  int g = blockIdx.x;
  int j = threadIdx.x;  // 256
  if (j < EMB) a[j] = vtmp[g * EMB + j];
  __syncthreads();
  float acc = b[j];
  #pragma unroll 8
  for (int k = 0; k < EMB; ++k) acc = fmaf(a[k], W[k * 256 + j], acc);
  u1[g * 256 + j] = acc;
  atomicAdd(&vs1raw[j], acc);
  atomicAdd(&vs1raw[256 + j], acc * acc);
}

__global__ void vmlp2_kernel(const float* __restrict__ u1, const float* __restrict__ vs1raw,
                             const float* __restrict__ g1, const float* __restrict__ b1,
                             const float* __restrict__ W, const float* __restrict__ b2,
                             float* __restrict__ u2, float* __restrict__ vs2raw) {
  __shared__ float a[256];
  __shared__ float sc[256], sh[256];
  int g = blockIdx.x;
  int j = threadIdx.x;  // 128
  for (int k = j; k < 256; k += EMB) {
    float s = vs1raw[k], q = vs1raw[256 + k];
    float mean = s / (float)NGR;
    float var = q / (float)NGR - mean * mean;
    float scl = g1[k] * rsqrtf(var + BN_EPS);
    sc[k] = scl;
    sh[k] = b1[k] - mean * scl;
  }
  __syncthreads();
  for (int k = j; k < 256; k += EMB)
    a[k] = fmaxf(fmaf(u1[g * 256 + k], sc[k], sh[k]), 0.f);
  __syncthreads();
  float acc = b2[j];
  #pragma unroll 8
  for (int k = 0; k < 256; ++k) acc = fmaf(a[k], W[k * EMB + j], acc);
  u2[g * EMB + j] = acc;
  atomicAdd(&vs2raw[j], acc);
  atomicAdd(&vs2raw[EMB + j], acc * acc);
}

__global__ void vnupd_kernel(const float* __restrict__ u2, const float* __restrict__ vs2raw,
                             const float* __restrict__ g2, const float* __restrict__ b2,
                             float* __restrict__ vn) {
  __shared__ float sc[EMB], sh[EMB];
  int g = blockIdx.x;
  int j = threadIdx.x;  // 128
  {
    float s = vs2raw[j], q = vs2raw[EMB + j];
    float mean = s / (float)NGR;
    float var = q / (float)NGR - mean * mean;
    float scl = g2[j] * rsqrtf(var + BN_EPS);
    sc[j] = scl;
    sh[j] = b2[j] - mean * scl;
  }
  __syncthreads();
  vn[g * EMB + j] = fmaxf(fmaf(u2[g * EMB + j], sc[j], sh[j]), 0.f);
}

// ---------------- host launcher ----------------

extern "C" void kernel_launch(void* const* d_in, const int* in_sizes, int n_in,
                              void* d_out, int out_size, void* d_ws, size_t ws_size,
                              hipStream_t stream) {
  const float* x        = (const float*)d_in[0];
  const int*   ei       = (const int*)d_in[1];
  const float* eattr    = (const float*)d_in[2];
  const int*   batch    = (const int*)d_in[3];
  const float* node_W   = (const float*)d_in[4];
  const float* node_b   = (const float*)d_in[5];
  const float* vn_emb   = (const float*)d_in[6];
  const float* eps      = (const float*)d_in[7];
  const float* edge_W   = (const float*)d_in[8];
  const float* edge_b   = (const float*)d_in[9];
  const float* conv_W1  = (const float*)d_in[10];
  const float* conv_b1  = (const float*)d_in[11];
  const float* cbn_g    = (const float*)d_in[12];
  const float* cbn_b    = (const float*)d_in[13];
  const float* conv_W2  = (const float*)d_in[14];
  const float* conv_b2  = (const float*)d_in[15];
  const float* bn_g     = (const float*)d_in[16];
  const float* bn_b     = (const float*)d_in[17];
  const float* vW1      = (const float*)d_in[18];
  const float* vb1      = (const float*)d_in[19];
  const float* vbn1_g   = (const float*)d_in[20];
  const float* vbn1_b   = (const float*)d_in[21];
  const float* vW2      = (const float*)d_in[22];
  const float* vb2      = (const float*)d_in[23];
  const float* vbn2_g   = (const float*)d_in[24];
  const float* vbn2_b   = (const float*)d_in[25];

  const int n = in_sizes[0] / 9;   // 50000
  const int E = in_sizes[1] / 2;   // 600000
  const int nb = (n + 2047) / 2048;

  // -------- workspace carve (aligned 256B) --------
  char* p = (char*)d_ws;
  auto carve = [&](size_t bytes) {
    char* r = p;
    p += (bytes + 255) & ~(size_t)255;
    return r;
  };
  float* h_in   = (float*)carve((size_t)n * EMB * 4);
  ushort* h16   = (ushort*)carve((size_t)n * EMB * 2);
  float* t1     = (float*)carve((size_t)n * 256 * 4);
  float* t2     = (float*)carve((size_t)n * EMB * 4);
  ushort* tpre_h = (ushort*)carve((size_t)n * EMB * 2);
  ushort* tpre_l = (ushort*)carve((size_t)n * EMB * 2);
  float* vn     = (float*)carve((size_t)NGR * EMB * 4);
  float* vnsum  = (float*)carve((size_t)NGR * EMB * 4);
  float* u1     = (float*)carve((size_t)NGR * 256 * 4);
  float* u2     = (float*)carve((size_t)NGR * EMB * 4);
  float* stats  = (float*)carve((size_t)NLAYER * 1536 * 4);
  int* deg      = (int*)carve((size_t)n * 4);
  int* rstart   = (int*)carve((size_t)(n + 1) * 4);
  int* cursor   = (int*)carve((size_t)n * 4);
  EPack* epk    = (EPack*)carve((size_t)E * sizeof(EPack));
  int* gstart   = (int*)carve((size_t)(NGR + 1) * 4);
  int* bsum     = (int*)carve((size_t)64 * 4);
  int* boff     = (int*)carve((size_t)64 * 4);
  ushort* wt1h  = (ushort*)carve((size_t)NLAYER * 256 * 128 * 2);
  ushort* wt1l  = (ushort*)carve((size_t)NLAYER * 256 * 128 * 2);
  ushort* wt2h  = (ushort*)carve((size_t)NLAYER * 128 * 256 * 2);
  ushort* wt2l  = (ushort*)carve((size_t)NLAYER * 128 * 256 * 2);
  float* h0     = t1;  // alias: h0 consumed (by l=0 hin) before t1 written

  auto s1  = [&](int l) { return stats + (size_t)l * 1536; };
  auto s2  = [&](int l) { return stats + (size_t)l * 1536 + 512; };
  auto vs1 = [&](int l) { return stats + (size_t)l * 1536 + 768; };
  auto vs2 = [&](int l) { return stats + (size_t)l * 1536 + 1280; };

  // -------- setup --------
  init_kernel<<<(NGR * EMB + 255) / 256, 256, 0, stream>>>(deg, n, stats, NLAYER * 1536, vn, vn_emb);
  deg_kernel<<<(E + 255) / 256, 256, 0, stream>>>(ei, deg, E);
  scan1_kernel<<<nb, 256, 0, stream>>>(deg, bsum, n);
  scan2_kernel<<<1, 64, 0, stream>>>(bsum, boff, rstart + n, nb);
  scan3_kernel<<<nb, 256, 0, stream>>>(deg, boff, rstart, cursor, n);
  fill_kernel<<<(E + 255) / 256, 256, 0, stream>>>(ei, cursor, eattr, epk, E);
  bounds_kernel<<<(NGR + 1 + 255) / 256, 256, 0, stream>>>(batch, gstart, n, NGR);
  {
    int tot1 = NLAYER * 128 * 256;   // conv_W1: K=128, N=256
    wtrans_kernel<<<(tot1 + 255) / 256, 256, 0, stream>>>(conv_W1, wt1h, wt1l, 128, 256, tot1);
    int tot2 = NLAYER * 256 * 128;   // conv_W2: K=256, N=128
    wtrans_kernel<<<(tot2 + 255) / 256, 256, 0, stream>>>(conv_W2, wt2h, wt2l, 256, 128, tot2);
  }
  encoder_kernel<<<2048, 256, 0, stream>>>(x, node_W, node_b, h0, n);

  const int mtiles = (n + 127) / 128;

  for (int l = 0; l < NLAYER; ++l) {
    if (l == 0)
      hin_kernel<true><<<4096, 256, 0, stream>>>(h0, vn, batch, nullptr, nullptr, nullptr,
                                                 h_in, h16, n);
    else
      hin_kernel<false><<<4096, 256, 0, stream>>>(t2, vn, batch, s2(l - 1),
                                                  bn_g + (size_t)(l - 1) * EMB,
                                                  bn_b + (size_t)(l - 1) * EMB, h_in, h16, n);
    if (l < NLAYER - 1)
      vnsum_kernel<<<NGR, EMB, 0, stream>>>(h_in, gstart, vn, vnsum);

    agg_kernel<<<n, EMB, 0, stream>>>(h_in, h16, rstart, epk,
                                      edge_W + (size_t)l * 10 * EMB,
                                      edge_b + (size_t)l * EMB, eps, l, tpre_h, tpre_l, n);

    gemm_mfma<128, 256, false, true, true><<<dim3(mtiles, 2), 256, 0, stream>>>(
        nullptr, tpre_h, tpre_l, wt1h + (size_t)l * 256 * 128, wt1l + (size_t)l * 256 * 128,
        conv_b1 + (size_t)l * 256, t1, n, nullptr, nullptr, nullptr, s1(l));

    gemm_mfma<256, 128, true, true, false><<<dim3(mtiles, 1), 256, 0, stream>>>(
        t1, nullptr, nullptr, wt2h + (size_t)l * 128 * 256, wt2l + (size_t)l * 128 * 256,
        conv_b2 + (size_t)l * 128, t2, n,
        s1(l), cbn_g + (size_t)l * 256, cbn_b + (size_t)l * 256, s2(l));

    if (l < NLAYER - 1) {
      vmlp1_kernel<<<NGR, 256, 0, stream>>>(vnsum, vW1 + (size_t)l * 128 * 256,
                                            vb1 + (size_t)l * 256, u1, vs1(l));
      vmlp2_kernel<<<NGR, EMB, 0, stream>>>(u1, vs1(l), vbn1_g + (size_t)l * 256,
                                            vbn1_b + (size_t)l * 256,
                                            vW2 + (size_t)l * 256 * 128,
                                            vb2 + (size_t)l * EMB, u2, vs2(l));
      vnupd_kernel<<<NGR, EMB, 0, stream>>>(u2, vs2(l), vbn2_g + (size_t)l * EMB,
                                            vbn2_b + (size_t)l * EMB, vn);
    }
  }

  out_kernel<<<4096, 256, 0, stream>>>(t2, s2(NLAYER - 1),
                                       bn_g + (size_t)(NLAYER - 1) * EMB,
                                       bn_b + (size_t)(NLAYER - 1) * EMB,
                                       (float*)d_out, n);
}

// Round 11
// 1131.288 us; speedup vs baseline: 1.1319x; 1.1234x over previous
//
#include <hip/hip_runtime.h>

// GIN + virtual-node GNN, 5 layers.
// R11: (a) agg edge-encoder via v_dot2_f32_f16 (fdot2) on f16-packed edge
//      features (5 dots replace 20 VALU ops/edge-thread; f16 > bf16 precision)
//      (b) agg grid-stride 8192 blocks (~6 nodes each) -> W-staging amortized
//      6x at full occupancy (R7's failure was occupancy, not chunking per se)
//      (c) vnsum split 4-way per graph, partials summed in vmlp1 (no atomics).

#define EMB 128
#define NGR 512
#define NLAYER 5
static constexpr float BN_EPS = 1e-5f;

typedef __attribute__((ext_vector_type(8))) short short8v;  // 8 bf16 = 4 VGPR
typedef __attribute__((ext_vector_type(4))) float f32x4;
typedef _Float16 half2v __attribute__((ext_vector_type(2)));

#if defined(__has_builtin)
#if __has_builtin(__builtin_amdgcn_fdot2)
#define HAS_FDOT2 1
#endif
#endif

__device__ __forceinline__ ushort f2bf(float f) {
  union { float f; unsigned u; } c; c.f = f;
  return (ushort)((c.u + 0x7FFFu + ((c.u >> 16) & 1u)) >> 16);
}
__device__ __forceinline__ float bf2f(ushort h) {
  union { unsigned u; float f; } c; c.u = ((unsigned)h) << 16;
  return c.f;
}

// 32B packed edge record: src node + 5x half2 edge features
struct __attribute__((aligned(32))) EPack {
  int src;
  uint ea2[5];   // 5 packed half2
  uint pad[2];
};

// ---------------- setup kernels ----------------

__global__ void init_kernel(int* __restrict__ deg, int ndeg,
                            float* __restrict__ stats, int nstats,
                            float* __restrict__ vn, const float* __restrict__ vn_emb) {
  int idx = blockIdx.x * blockDim.x + threadIdx.x;
  if (idx < ndeg) deg[idx] = 0;
  if (idx < nstats) stats[idx] = 0.f;
  if (idx < NGR * EMB) vn[idx] = vn_emb[idx & (EMB - 1)];
}

__global__ void deg_kernel(const int* __restrict__ ei, int* __restrict__ deg, int E) {
  int e = blockIdx.x * blockDim.x + threadIdx.x;
  if (e < E) atomicAdd(&deg[ei[E + e]], 1);
}

// ---- hierarchical prefix scan over deg[n] (2048 elems per 256-thr block) ----

__global__ void scan1_kernel(const int* __restrict__ deg, int* __restrict__ bsum, int n) {
  __shared__ int ws[4];
  int t = threadIdx.x;
  int base = blockIdx.x * 2048 + t * 8;
  int s = 0;
  #pragma unroll
  for (int i = 0; i < 8; ++i) {
    int idx = base + i;
    if (idx < n) s += deg[idx];
  }
  #pragma unroll
  for (int off = 32; off; off >>= 1) s += __shfl_down(s, off);
  if ((t & 63) == 0) ws[t >> 6] = s;
  __syncthreads();
  if (t == 0) bsum[blockIdx.x] = ws[0] + ws[1] + ws[2] + ws[3];
}

// single 64-thread block; nb <= 64. boff = exclusive scan; *row_n = total.
__global__ void scan2_kernel(const int* __restrict__ bsum, int* __restrict__ boff,
                             int* __restrict__ row_n, int nb) {
  int t = threadIdx.x;
  int mine = (t < nb) ? bsum[t] : 0;
  int v = mine;
  #pragma unroll
  for (int off = 1; off < 64; off <<= 1) {
    int u = __shfl_up(v, off);
    if (t >= off) v += u;
  }
  if (t < nb) boff[t] = v - mine;
  if (t == nb - 1) *row_n = v;
}

__global__ __launch_bounds__(256) void scan3_kernel(const int* __restrict__ deg,
                                                    const int* __restrict__ boff,
                                                    int* __restrict__ row_start,
                                                    int* __restrict__ cursor, int n) {
  __shared__ int lsum[256];
  int t = threadIdx.x;
  int base = blockIdx.x * 2048 + t * 8;
  int loc[8];
  int s = 0;
  #pragma unroll
  for (int i = 0; i < 8; ++i) {
    int idx = base + i;
    int d = (idx < n) ? deg[idx] : 0;
    loc[i] = s;
    s += d;
  }
  lsum[t] = s;
  __syncthreads();
  #pragma unroll
  for (int off = 1; off < 256; off <<= 1) {
    int v2 = (t >= off) ? lsum[t - off] : 0;
    __syncthreads();
    lsum[t] += v2;
    __syncthreads();
  }
  int toff = boff[blockIdx.x] + lsum[t] - s;  // exclusive across grid
  #pragma unroll
  for (int i = 0; i < 8; ++i) {
    int idx = base + i;
    if (idx < n) {
      int rs = toff + loc[i];
      row_start[idx] = rs;
      cursor[idx] = rs;
    }
  }
}

// pack {src, f16 edge_attr pairs} into CSR position (once; reused all 5 layers)
__global__ void fill_kernel(const int* __restrict__ ei, int* __restrict__ cursor,
                            const float* __restrict__ eattr,
                            EPack* __restrict__ epk, int E) {
  int e = blockIdx.x * blockDim.x + threadIdx.x;
  if (e < E) {
    int d = ei[E + e];
    int pos = atomicAdd(&cursor[d], 1);
    EPack r;
    r.src = ei[e];
    const float* ea = eattr + (size_t)e * 10;
    #pragma unroll
    for (int k2 = 0; k2 < 5; ++k2) {
      union { uint u; half2v h; } cv;
      cv.h[0] = (_Float16)ea[2 * k2];
      cv.h[1] = (_Float16)ea[2 * k2 + 1];
      r.ea2[k2] = cv.u;
    }
    r.pad[0] = r.pad[1] = 0;
    epk[pos] = r;
  }
}

// graph_start[g] = lower_bound(batch, g); batch is sorted. Handles empty graphs.
__global__ void bounds_kernel(const int* __restrict__ batch, int* __restrict__ gstart,
                              int n, int ng) {
  int g = blockIdx.x * blockDim.x + threadIdx.x;
  if (g > ng) return;
  int lo = 0, hi = n;
  while (lo < hi) {
    int mid = (lo + hi) >> 1;
    if (batch[mid] < g) lo = mid + 1; else hi = mid;
  }
  gstart[g] = lo;
}

// W [L][K][N] -> Wth/Wtl [L][N][K] (transpose + bf16 hi/lo split), per flat idx
__global__ void wtrans_kernel(const float* __restrict__ W, ushort* __restrict__ Wth,
                              ushort* __restrict__ Wtl, int K, int N, int total) {
  int idx = blockIdx.x * blockDim.x + threadIdx.x;
  if (idx >= total) return;
  int kk = idx % K;
  int t = idx / K;
  int nn = t % N;
  int l = t / N;
  float v = W[((size_t)l * K + kk) * N + nn];
  ushort h = f2bf(v);
  Wth[idx] = h;
  Wtl[idx] = f2bf(v - bf2f(h));
}

// h0 = x @ node_W + node_b   (K=9, N=128)
__global__ void encoder_kernel(const float* __restrict__ x, const float* __restrict__ W,
                               const float* __restrict__ b, float* __restrict__ h0, int n) {
  __shared__ float Ws[9][EMB];
  __shared__ float bs[EMB];
  int t = threadIdx.x;
  if (t < EMB) {
    #pragma unroll
    for (int k = 0; k < 9; ++k) Ws[k][t] = W[k * EMB + t];
    bs[t] = b[t];
  }
  __syncthreads();
  int total = n * EMB;
  for (int idx = blockIdx.x * blockDim.x + t; idx < total; idx += gridDim.x * blockDim.x) {
    int i = idx >> 7, j = idx & 127;
    const float* xr = x + i * 9;
    float acc = bs[j];
    #pragma unroll
    for (int k = 0; k < 9; ++k) acc = fmaf(xr[k], Ws[k][j], acc);
    h0[idx] = acc;
  }
}

// ---------------- per-layer kernels ----------------

// h_in = (RAW ? src : relu(bn2(src))) + vn[batch]; also writes bf16 copy h16
template <bool RAW>
__global__ void hin_kernel(const float* __restrict__ src, const float* __restrict__ vn,
                           const int* __restrict__ batch, const float* __restrict__ s2raw,
                           const float* __restrict__ g2, const float* __restrict__ b2,
                           float* __restrict__ h_in, ushort* __restrict__ h16, int n) {
  __shared__ float sc[EMB], sh[EMB];
  if (!RAW) {
    int j = threadIdx.x;
    if (j < EMB) {
      float s = s2raw[j], q = s2raw[EMB + j];
      float mean = s / (float)n;
      float var = q / (float)n - mean * mean;
      float scl = g2[j] * rsqrtf(var + BN_EPS);
      sc[j] = scl;
      sh[j] = b2[j] - mean * scl;
    }
    __syncthreads();
  }
  int total = n * EMB;
  for (int idx = blockIdx.x * blockDim.x + threadIdx.x; idx < total; idx += gridDim.x * blockDim.x) {
    int i = idx >> 7, j = idx & 127;
    float v = src[idx];
    if (!RAW) v = fmaxf(fmaf(v, sc[j], sh[j]), 0.f);
    float hv = v + vn[batch[i] * EMB + j];
    h_in[idx] = hv;
    h16[idx] = f2bf(hv);
  }
}

// final output: d_out = bn2(t2)  (no relu, layer L-1)
__global__ void out_kernel(const float* __restrict__ t2, const float* __restrict__ s2raw,
                           const float* __restrict__ g2, const float* __restrict__ b2,
                           float* __restrict__ out, int n) {
  __shared__ float sc[EMB], sh[EMB];
  int j0 = threadIdx.x;
  if (j0 < EMB) {
    float s = s2raw[j0], q = s2raw[EMB + j0];
    float mean = s / (float)n;
    float var = q / (float)n - mean * mean;
    float scl = g2[j0] * rsqrtf(var + BN_EPS);
    sc[j0] = scl;
    sh[j0] = b2[j0] - mean * scl;
  }
  __syncthreads();
  int total = n * EMB;
  for (int idx = blockIdx.x * blockDim.x + threadIdx.x; idx < total; idx += gridDim.x * blockDim.x) {
    int j = idx & 127;
    out[idx] = fmaf(t2[idx], sc[j], sh[j]);
  }
}

// vnsum partials: grid (NGR, 4); chunk c of graph g -> vnsum4[c][g][:]
// (no atomics; vmlp1 sums the 4 partials + vn)
__global__ void vnsum_kernel(const float* __restrict__ h_in, const int* __restrict__ gstart,
                             float* __restrict__ vnsum4) {
  int g = blockIdx.x;
  int c = blockIdx.y;
  int j = threadIdx.x;
  int s0 = gstart[g], s1 = gstart[g + 1];
  int chunk = (s1 - s0 + 3) >> 2;
  int a = s0 + c * chunk;
  int b = min(s1, a + chunk);
  float acc = 0.f;
  for (int i = a; i < b; ++i) acc += h_in[(size_t)i * EMB + j];
  vnsum4[((size_t)c * NGR + g) * EMB + j] = acc;
}

// t_pre[i] = (1+eps)*h_in[i] + sum_{e: dst=i} relu(h16[src(e)] + ea(e) @ eW + eb)
// Grid-stride (~6 nodes/block, W staged once). fdot2 edge encoder.
__global__ __launch_bounds__(128) void agg_kernel(
    const float* __restrict__ h_in, const ushort* __restrict__ h16,
    const int* __restrict__ row_start, const EPack* __restrict__ epk,
    const float* __restrict__ eW, const float* __restrict__ eb,
    const float* __restrict__ eps_p, int l,
    ushort* __restrict__ tpre_h, ushort* __restrict__ tpre_l, int n) {
  __shared__ uint Wp[5][EMB];       // packed half2 weight pairs
  __shared__ float bia[EMB];
  int j = threadIdx.x;  // 128
  #pragma unroll
  for (int k2 = 0; k2 < 5; ++k2) {
    union { uint u; half2v h; } cv;
    cv.h[0] = (_Float16)eW[(2 * k2) * EMB + j];
    cv.h[1] = (_Float16)eW[(2 * k2 + 1) * EMB + j];
    Wp[k2][j] = cv.u;
  }
  bia[j] = eb[j];
  float epsv = 1.f + eps_p[l];
  __syncthreads();

  for (int i = blockIdx.x; i < n; i += gridDim.x) {
    int s0 = row_start[i], s1 = row_start[i + 1];
    float acc = epsv * h_in[(size_t)i * EMB + j];
    int p = s0;

    auto edot = [&](const EPack* ep) -> float {
      float v = bia[j];
      #pragma unroll
      for (int k2 = 0; k2 < 5; ++k2) {
        union { uint u; half2v h; } a, w;
        a.u = ep->ea2[k2];
        w.u = Wp[k2][j];
#ifdef HAS_FDOT2
        v = __builtin_amdgcn_fdot2(a.h, w.h, v, false);
#else
        v = fmaf((float)a.h[0], (float)w.h[0], v);
        v = fmaf((float)a.h[1], (float)w.h[1], v);
#endif
      }
      return v;
    };

    for (; p + 8 <= s1; p += 8) {
      int srcs[8];
      #pragma unroll
      for (int u = 0; u < 8; ++u) srcs[u] = epk[p + u].src;
      float hv[8];
      #pragma unroll
      for (int u = 0; u < 8; ++u) hv[u] = bf2f(h16[(size_t)srcs[u] * EMB + j]);
      #pragma unroll
      for (int u = 0; u < 8; ++u)
        acc += fmaxf(edot(epk + p + u) + hv[u], 0.f);
    }
    for (; p + 4 <= s1; p += 4) {
      int srcs[4];
      #pragma unroll
      for (int u = 0; u < 4; ++u) srcs[u] = epk[p + u].src;
      float hv[4];
      #pragma unroll
      for (int u = 0; u < 4; ++u) hv[u] = bf2f(h16[(size_t)srcs[u] * EMB + j]);
      #pragma unroll
      for (int u = 0; u < 4; ++u)
        acc += fmaxf(edot(epk + p + u) + hv[u], 0.f);
    }
    for (; p < s1; ++p) {
      float hv0 = bf2f(h16[(size_t)epk[p].src * EMB + j]);
      acc += fmaxf(edot(epk + p) + hv0, 0.f);
    }
    ushort hh = f2bf(acc);
    tpre_h[(size_t)i * EMB + j] = hh;
    tpre_l[(size_t)i * EMB + j] = f2bf(acc - bf2f(hh));
  }
}

// ---------------- bf16x3 split-MFMA GEMM ----------------
// APRE: A supplied pre-split (Ath/Atl, bf16 hi/lo row-major [M][KT]) -> pure
// copy staging. Else A fp32 with optional BN+relu, split during staging.
template <int KT, int NT, bool BN_A, bool STATS, bool APRE>
__global__ __launch_bounds__(256) void gemm_mfma(
    const float* __restrict__ A, const ushort* __restrict__ Ath,
    const ushort* __restrict__ Atl,
    const ushort* __restrict__ Bth, const ushort* __restrict__ Btl,
    const float* __restrict__ bias,
    float* __restrict__ C, int M,
    const float* __restrict__ bnraw, const float* __restrict__ bng,
    const float* __restrict__ bnb, float* __restrict__ statraw) {
  constexpr int BM = 128, BN = 128, BK = 32;
  constexpr int LDK = BK + 8;
  constexpr int KSTEPS = KT / BK;
  __shared__ ushort Ah[BM][LDK], Al[BM][LDK];
  __shared__ ushort Bh[BN][LDK], Bl[BN][LDK];
  __shared__ float red[8][BN], redq[8][BN];
  constexpr int SCN = BN_A ? KT : 1;
  __shared__ float scS[SCN], shS[SCN];

  int tid = threadIdx.x;
  if (BN_A) {
    for (int k = tid; k < KT; k += 256) {
      float s = bnraw[k], q = bnraw[KT + k];
      float mean = s / (float)M;
      float var = q / (float)M - mean * mean;
      float scl = bng[k] * rsqrtf(var + BN_EPS);
      scS[k] = scl;
      shS[k] = bnb[k] - mean * scl;
    }
  }

  int wv = tid >> 6, lane = tid & 63;
  int wr = wv >> 1, wc = wv & 1;
  int lr = lane & 15, kg = lane >> 4;
  int bm0 = blockIdx.x * BM;
  int gc0 = blockIdx.y * BN;

  int sr = tid >> 1;
  int skq = (tid & 1) * 16;

  f32x4 acc[4][4];
  #pragma unroll
  for (int fm = 0; fm < 4; ++fm)
    #pragma unroll
    for (int fn = 0; fn < 4; ++fn) {
      float b = bias[gc0 + wc * 64 + fn * 16 + lr];
      acc[fm][fn][0] = b; acc[fm][fn][1] = b; acc[fm][fn][2] = b; acc[fm][fn][3] = b;
    }

  for (int kt = 0; kt < KSTEPS; ++kt) {
    __syncthreads();
    {
      int grow = bm0 + sr;
      if (APRE) {
        short8v z;
        #pragma unroll
        for (int q2 = 0; q2 < 8; ++q2) z[q2] = 0;
        if (grow < M) {
          const ushort* aph = Ath + (size_t)grow * KT + kt * BK + skq;
          const ushort* apl = Atl + (size_t)grow * KT + kt * BK + skq;
          *(short8v*)&Ah[sr][skq] = *(const short8v*)aph;
          *(short8v*)&Ah[sr][skq + 8] = *(const short8v*)(aph + 8);
          *(short8v*)&Al[sr][skq] = *(const short8v*)apl;
          *(short8v*)&Al[sr][skq + 8] = *(const short8v*)(apl + 8);
        } else {
          *(short8v*)&Ah[sr][skq] = z;
          *(short8v*)&Ah[sr][skq + 8] = z;
          *(short8v*)&Al[sr][skq] = z;
          *(short8v*)&Al[sr][skq + 8] = z;
        }
      } else {
        const float* ap = A + (size_t)grow * KT + kt * BK + skq;
        short8v ah0, al0, ah1, al1;
        #pragma unroll
        for (int u = 0; u < 4; ++u) {
          float4 v = (grow < M) ? *reinterpret_cast<const float4*>(ap + u * 4)
                                : make_float4(0.f, 0.f, 0.f, 0.f);
          if (BN_A) {
            int gk = kt * BK + skq + u * 4;
            v.x = fmaxf(fmaf(v.x, scS[gk + 0], shS[gk + 0]), 0.f);
            v.y = fmaxf(fmaf(v.y, scS[gk + 1], shS[gk + 1]), 0.f);
            v.z = fmaxf(fmaf(v.z, scS[gk + 2], shS[gk + 2]), 0.f);
            v.w = fmaxf(fmaf(v.w, scS[gk + 3], shS[gk + 3]), 0.f);
          }
          float vv0 = v.x, vv1 = v.y, vv2 = v.z, vv3 = v.w;
          ushort h0 = f2bf(vv0), h1 = f2bf(vv1), h2 = f2bf(vv2), h3 = f2bf(vv3);
          ushort w0 = f2bf(vv0 - bf2f(h0)), w1 = f2bf(vv1 - bf2f(h1));
          ushort w2 = f2bf(vv2 - bf2f(h2)), w3 = f2bf(vv3 - bf2f(h3));
          if (u < 2) {
            ah0[u * 4 + 0] = (short)h0; ah0[u * 4 + 1] = (short)h1;
            ah0[u * 4 + 2] = (short)h2; ah0[u * 4 + 3] = (short)h3;
            al0[u * 4 + 0] = (short)w0; al0[u * 4 + 1] = (short)w1;
            al0[u * 4 + 2] = (short)w2; al0[u * 4 + 3] = (short)w3;
          } else {
            ah1[(u - 2) * 4 + 0] = (short)h0; ah1[(u - 2) * 4 + 1] = (short)h1;
            ah1[(u - 2) * 4 + 2] = (short)h2; ah1[(u - 2) * 4 + 3] = (short)h3;
            al1[(u - 2) * 4 + 0] = (short)w0; al1[(u - 2) * 4 + 1] = (short)w1;
            al1[(u - 2) * 4 + 2] = (short)w2; al1[(u - 2) * 4 + 3] = (short)w3;
          }
        }
        *(short8v*)&Ah[sr][skq] = ah0;
        *(short8v*)&Ah[sr][skq + 8] = ah1;
        *(short8v*)&Al[sr][skq] = al0;
        *(short8v*)&Al[sr][skq + 8] = al1;
      }
    }
    {
      const ushort* bph = Bth + (size_t)(gc0 + sr) * KT + kt * BK + skq;
      const ushort* bpl = Btl + (size_t)(gc0 + sr) * KT + kt * BK + skq;
      *(short8v*)&Bh[sr][skq] = *(const short8v*)bph;
      *(short8v*)&Bh[sr][skq + 8] = *(const short8v*)(bph + 8);
      *(short8v*)&Bl[sr][skq] = *(const short8v*)bpl;
      *(short8v*)&Bl[sr][skq + 8] = *(const short8v*)(bpl + 8);
    }
    __syncthreads();
    short8v a_h[4], a_l[4], b_h[4], b_l[4];
    #pragma unroll
    for (int f = 0; f < 4; ++f) {
      a_h[f] = *(const short8v*)&Ah[wr * 64 + f * 16 + lr][kg * 8];
      a_l[f] = *(const short8v*)&Al[wr * 64 + f * 16 + lr][kg * 8];
      b_h[f] = *(const short8v*)&Bh[wc * 64 + f * 16 + lr][kg * 8];
      b_l[f] = *(const short8v*)&Bl[wc * 64 + f * 16 + lr][kg * 8];
    }
    #pragma unroll
    for (int fm = 0; fm < 4; ++fm)
      #pragma unroll
      for (int fn = 0; fn < 4; ++fn) {
        acc[fm][fn] = __builtin_amdgcn_mfma_f32_16x16x32_bf16(a_h[fm], b_h[fn], acc[fm][fn], 0, 0, 0);
        acc[fm][fn] = __builtin_amdgcn_mfma_f32_16x16x32_bf16(a_h[fm], b_l[fn], acc[fm][fn], 0, 0, 0);
        acc[fm][fn] = __builtin_amdgcn_mfma_f32_16x16x32_bf16(a_l[fm], b_h[fn], acc[fm][fn], 0, 0, 0);
      }
  }

  #pragma unroll
  for (int fm = 0; fm < 4; ++fm) {
    int rb = bm0 + wr * 64 + fm * 16 + kg * 4;
    #pragma unroll
    for (int i = 0; i < 4; ++i) {
      int grow = rb + i;
      if (grow < M) {
        float* cp = C + (size_t)grow * NT + gc0 + wc * 64 + lr;
        #pragma unroll
        for (int fn = 0; fn < 4; ++fn) cp[fn * 16] = acc[fm][fn][i];
      }
    }
  }

  if (STATS) {
    #pragma unroll
    for (int fn = 0; fn < 4; ++fn) {
      float s = 0.f, q = 0.f;
      #pragma unroll
      for (int fm = 0; fm < 4; ++fm) {
        int rb = bm0 + wr * 64 + fm * 16 + kg * 4;
        #pragma unroll
        for (int i = 0; i < 4; ++i) {
          if (rb + i < M) {
            float v = acc[fm][fn][i];
            s += v;
            q = fmaf(v, v, q);
          }
        }
      }
      red[wr * 4 + kg][wc * 64 + fn * 16 + lr] = s;
      redq[wr * 4 + kg][wc * 64 + fn * 16 + lr] = q;
    }
    __syncthreads();
    if (tid < BN) {
      float s = 0.f, q = 0.f;
      #pragma unroll
      for (int r2 = 0; r2 < 8; ++r2) {
        s += red[r2][tid];
        q += redq[r2][tid];
      }
      int gcol = gc0 + tid;
      atomicAdd(&statraw[gcol], s);
      atomicAdd(&statraw[NT + gcol], q);
    }
  }
}

// ---------------- virtual-node MLP (tiny: 512 rows) ----------------

// u1[g] = (vn[g] + sum4 partials) @ W(128x256) + b ; fused stats
__global__ void vmlp1_kernel(const float* __restrict__ vnsum4, const float* __restrict__ vn,
                             const float* __restrict__ W,
                             const float* __restrict__ b, float* __restrict__ u1,
                             float* __restrict__ vs1raw) {
  __shared__ float a[EMB];
  int g = blockIdx.x;
  int j = threadIdx.x;  // 256
  if (j < EMB) {
    float s = vn[g * EMB + j];
    #pragma unroll
    for (int c = 0; c < 4; ++c) s += vnsum4[((size_t)c * NGR + g) * EMB + j];
    a[j] = s;
  }
  __syncthreads();
  float acc = b[j];
  #pragma unroll 8
  for (int k = 0; k < EMB; ++k) acc = fmaf(a[k], W[k * 256 + j], acc);
  u1[g * 256 + j] = acc;
  atomicAdd(&vs1raw[j], acc);
  atomicAdd(&vs1raw[256 + j], acc * acc);
}

__global__ void vmlp2_kernel(const float* __restrict__ u1, const float* __restrict__ vs1raw,
                             const float* __restrict__ g1, const float* __restrict__ b1,
                             const float* __restrict__ W, const float* __restrict__ b2,
                             float* __restrict__ u2, float* __restrict__ vs2raw) {
  __shared__ float a[256];
  __shared__ float sc[256], sh[256];
  int g = blockIdx.x;
  int j = threadIdx.x;  // 128
  for (int k = j; k < 256; k += EMB) {
    float s = vs1raw[k], q = vs1raw[256 + k];
    float mean = s / (float)NGR;
    float var = q / (float)NGR - mean * mean;
    float scl = g1[k] * rsqrtf(var + BN_EPS);
    sc[k] = scl;
    sh[k] = b1[k] - mean * scl;
  }
  __syncthreads();
  for (int k = j; k < 256; k += EMB)
    a[k] = fmaxf(fmaf(u1[g * 256 + k], sc[k], sh[k]), 0.f);
  __syncthreads();
  float acc = b2[j];
  #pragma unroll 8
  for (int k = 0; k < 256; ++k) acc = fmaf(a[k], W[k * EMB + j], acc);
  u2[g * EMB + j] = acc;
  atomicAdd(&vs2raw[j], acc);
  atomicAdd(&vs2raw[EMB + j], acc * acc);
}

__global__ void vnupd_kernel(const float* __restrict__ u2, const float* __restrict__ vs2raw,
                             const float* __restrict__ g2, const float* __restrict__ b2,
                             float* __restrict__ vn) {
  __shared__ float sc[EMB], sh[EMB];
  int g = blockIdx.x;
  int j = threadIdx.x;  // 128
  {
    float s = vs2raw[j], q = vs2raw[EMB + j];
    float mean = s / (float)NGR;
    float var = q / (float)NGR - mean * mean;
    float scl = g2[j] * rsqrtf(var + BN_EPS);
    sc[j] = scl;
    sh[j] = b2[j] - mean * scl;
  }
  __syncthreads();
  vn[g * EMB + j] = fmaxf(fmaf(u2[g * EMB + j], sc[j], sh[j]), 0.f);
}

// ---------------- host launcher ----------------

extern "C" void kernel_launch(void* const* d_in, const int* in_sizes, int n_in,
                              void* d_out, int out_size, void* d_ws, size_t ws_size,
                              hipStream_t stream) {
  const float* x        = (const float*)d_in[0];
  const int*   ei       = (const int*)d_in[1];
  const float* eattr    = (const float*)d_in[2];
  const int*   batch    = (const int*)d_in[3];
  const float* node_W   = (const float*)d_in[4];
  const float* node_b   = (const float*)d_in[5];
  const float* vn_emb   = (const float*)d_in[6];
  const float* eps      = (const float*)d_in[7];
  const float* edge_W   = (const float*)d_in[8];
  const float* edge_b   = (const float*)d_in[9];
  const float* conv_W1  = (const float*)d_in[10];
  const float* conv_b1  = (const float*)d_in[11];
  const float* cbn_g    = (const float*)d_in[12];
  const float* cbn_b    = (const float*)d_in[13];
  const float* conv_W2  = (const float*)d_in[14];
  const float* conv_b2  = (const float*)d_in[15];
  const float* bn_g     = (const float*)d_in[16];
  const float* bn_b     = (const float*)d_in[17];
  const float* vW1      = (const float*)d_in[18];
  const float* vb1      = (const float*)d_in[19];
  const float* vbn1_g   = (const float*)d_in[20];
  const float* vbn1_b   = (const float*)d_in[21];
  const float* vW2      = (const float*)d_in[22];
  const float* vb2      = (const float*)d_in[23];
  const float* vbn2_g   = (const float*)d_in[24];
  const float* vbn2_b   = (const float*)d_in[25];

  const int n = in_sizes[0] / 9;   // 50000
  const int E = in_sizes[1] / 2;   // 600000
  const int nb = (n + 2047) / 2048;

  // -------- workspace carve (aligned 256B) --------
  char* p = (char*)d_ws;
  auto carve = [&](size_t bytes) {
    char* r = p;
    p += (bytes + 255) & ~(size_t)255;
    return r;
  };
  float* h_in   = (float*)carve((size_t)n * EMB * 4);
  ushort* h16   = (ushort*)carve((size_t)n * EMB * 2);
  float* t1     = (float*)carve((size_t)n * 256 * 4);
  float* t2     = (float*)carve((size_t)n * EMB * 4);
  ushort* tpre_h = (ushort*)carve((size_t)n * EMB * 2);
  ushort* tpre_l = (ushort*)carve((size_t)n * EMB * 2);
  float* vn     = (float*)carve((size_t)NGR * EMB * 4);
  float* vnsum4 = (float*)carve((size_t)4 * NGR * EMB * 4);
  float* u1     = (float*)carve((size_t)NGR * 256 * 4);
  float* u2     = (float*)carve((size_t)NGR * EMB * 4);
  float* stats  = (float*)carve((size_t)NLAYER * 1536 * 4);
  int* deg      = (int*)carve((size_t)n * 4);
  int* rstart   = (int*)carve((size_t)(n + 1) * 4);
  int* cursor   = (int*)carve((size_t)n * 4);
  EPack* epk    = (EPack*)carve((size_t)E * sizeof(EPack));
  int* gstart   = (int*)carve((size_t)(NGR + 1) * 4);
  int* bsum     = (int*)carve((size_t)64 * 4);
  int* boff     = (int*)carve((size_t)64 * 4);
  ushort* wt1h  = (ushort*)carve((size_t)NLAYER * 256 * 128 * 2);
  ushort* wt1l  = (ushort*)carve((size_t)NLAYER * 256 * 128 * 2);
  ushort* wt2h  = (ushort*)carve((size_t)NLAYER * 128 * 256 * 2);
  ushort* wt2l  = (ushort*)carve((size_t)NLAYER * 128 * 256 * 2);
  float* h0     = t1;  // alias: h0 consumed (by l=0 hin) before t1 written

  auto s1  = [&](int l) { return stats + (size_t)l * 1536; };
  auto s2  = [&](int l) { return stats + (size_t)l * 1536 + 512; };
  auto vs1 = [&](int l) { return stats + (size_t)l * 1536 + 768; };
  auto vs2 = [&](int l) { return stats + (size_t)l * 1536 + 1280; };

  // -------- setup --------
  init_kernel<<<(NGR * EMB + 255) / 256, 256, 0, stream>>>(deg, n, stats, NLAYER * 1536, vn, vn_emb);
  deg_kernel<<<(E + 255) / 256, 256, 0, stream>>>(ei, deg, E);
  scan1_kernel<<<nb, 256, 0, stream>>>(deg, bsum, n);
  scan2_kernel<<<1, 64, 0, stream>>>(bsum, boff, rstart + n, nb);
  scan3_kernel<<<nb, 256, 0, stream>>>(deg, boff, rstart, cursor, n);
  fill_kernel<<<(E + 255) / 256, 256, 0, stream>>>(ei, cursor, eattr, epk, E);
  bounds_kernel<<<(NGR + 1 + 255) / 256, 256, 0, stream>>>(batch, gstart, n, NGR);
  {
    int tot1 = NLAYER * 128 * 256;   // conv_W1: K=128, N=256
    wtrans_kernel<<<(tot1 + 255) / 256, 256, 0, stream>>>(conv_W1, wt1h, wt1l, 128, 256, tot1);
    int tot2 = NLAYER * 256 * 128;   // conv_W2: K=256, N=128
    wtrans_kernel<<<(tot2 + 255) / 256, 256, 0, stream>>>(conv_W2, wt2h, wt2l, 256, 128, tot2);
  }
  encoder_kernel<<<2048, 256, 0, stream>>>(x, node_W, node_b, h0, n);

  const int mtiles = (n + 127) / 128;

  for (int l = 0; l < NLAYER; ++l) {
    if (l == 0)
      hin_kernel<true><<<4096, 256, 0, stream>>>(h0, vn, batch, nullptr, nullptr, nullptr,
                                                 h_in, h16, n);
    else
      hin_kernel<false><<<4096, 256, 0, stream>>>(t2, vn, batch, s2(l - 1),
                                                  bn_g + (size_t)(l - 1) * EMB,
                                                  bn_b + (size_t)(l - 1) * EMB, h_in, h16, n);
    if (l < NLAYER - 1)
      vnsum_kernel<<<dim3(NGR, 4), EMB, 0, stream>>>(h_in, gstart, vnsum4);

    agg_kernel<<<8192, EMB, 0, stream>>>(h_in, h16, rstart, epk,
                                         edge_W + (size_t)l * 10 * EMB,
                                         edge_b + (size_t)l * EMB, eps, l, tpre_h, tpre_l, n);

    gemm_mfma<128, 256, false, true, true><<<dim3(mtiles, 2), 256, 0, stream>>>(
        nullptr, tpre_h, tpre_l, wt1h + (size_t)l * 256 * 128, wt1l + (size_t)l * 256 * 128,
        conv_b1 + (size_t)l * 256, t1, n, nullptr, nullptr, nullptr, s1(l));

    gemm_mfma<256, 128, true, true, false><<<dim3(mtiles, 1), 256, 0, stream>>>(
        t1, nullptr, nullptr, wt2h + (size_t)l * 128 * 256, wt2l + (size_t)l * 128 * 256,
        conv_b2 + (size_t)l * 128, t2, n,
        s1(l), cbn_g + (size_t)l * 256, cbn_b + (size_t)l * 256, s2(l));

    if (l < NLAYER - 1) {
      vmlp1_kernel<<<NGR, 256, 0, stream>>>(vnsum4, vn, vW1 + (size_t)l * 128 * 256,
                                            vb1 + (size_t)l * 256, u1, vs1(l));
      vmlp2_kernel<<<NGR, EMB, 0, stream>>>(u1, vs1(l), vbn1_g + (size_t)l * 256,
                                            vbn1_b + (size_t)l * 256,
                                            vW2 + (size_t)l * 256 * 128,
                                            vb2 + (size_t)l * EMB, u2, vs2(l));
      vnupd_kernel<<<NGR, EMB, 0, stream>>>(u2, vs2(l), vbn2_g + (size_t)l * EMB,
                                            vbn2_b + (size_t)l * EMB, vn);
    }
  }

  out_kernel<<<4096, 256, 0, stream>>>(t2, s2(NLAYER - 1),
                                       bn_g + (size_t)(NLAYER - 1) * EMB,
                                       bn_b + (size_t)(NLAYER - 1) * EMB,
                                       (float*)d_out, n);
}

// Round 13
// 1114.007 us; speedup vs baseline: 1.1494x; 1.0155x over previous
//
#include <hip/hip_runtime.h>

// GIN + virtual-node GNN, 5 layers.
// R13 == R12 (infra failure, resubmit):
//      (a) gemm bf16x2 - weights rounded to bf16 (drop Ah@Bl product; A stays
//      hi+lo). -33% MFMA instrs, -50% B LDS/traffic. Standard bf16-weight
//      quantization, error ~2^-9 rel per gemm.
//      (b) hin/out vectorized float4/ushort4 (G13).
//      R11 agg (fdot2 + grid-stride) unchanged.

#define EMB 128
#define NGR 512
#define NLAYER 5
static constexpr float BN_EPS = 1e-5f;

typedef __attribute__((ext_vector_type(8))) short short8v;  // 8 bf16 = 4 VGPR
typedef __attribute__((ext_vector_type(4))) float f32x4;
typedef _Float16 half2v __attribute__((ext_vector_type(2)));

#if defined(__has_builtin)
#if __has_builtin(__builtin_amdgcn_fdot2)
#define HAS_FDOT2 1
#endif
#endif

__device__ __forceinline__ ushort f2bf(float f) {
  union { float f; unsigned u; } c; c.f = f;
  return (ushort)((c.u + 0x7FFFu + ((c.u >> 16) & 1u)) >> 16);
}
__device__ __forceinline__ float bf2f(ushort h) {
  union { unsigned u; float f; } c; c.u = ((unsigned)h) << 16;
  return c.f;
}

// 32B packed edge record: src node + 5x half2 edge features
struct __attribute__((aligned(32))) EPack {
  int src;
  uint ea2[5];   // 5 packed half2
  uint pad[2];
};

// ---------------- setup kernels ----------------

__global__ void init_kernel(int* __restrict__ deg, int ndeg,
                            float* __restrict__ stats, int nstats,
                            float* __restrict__ vn, const float* __restrict__ vn_emb) {
  int idx = blockIdx.x * blockDim.x + threadIdx.x;
  if (idx < ndeg) deg[idx] = 0;
  if (idx < nstats) stats[idx] = 0.f;
  if (idx < NGR * EMB) vn[idx] = vn_emb[idx & (EMB - 1)];
}

__global__ void deg_kernel(const int* __restrict__ ei, int* __restrict__ deg, int E) {
  int e = blockIdx.x * blockDim.x + threadIdx.x;
  if (e < E) atomicAdd(&deg[ei[E + e]], 1);
}

// ---- hierarchical prefix scan over deg[n] (2048 elems per 256-thr block) ----

__global__ void scan1_kernel(const int* __restrict__ deg, int* __restrict__ bsum, int n) {
  __shared__ int ws[4];
  int t = threadIdx.x;
  int base = blockIdx.x * 2048 + t * 8;
  int s = 0;
  #pragma unroll
  for (int i = 0; i < 8; ++i) {
    int idx = base + i;
    if (idx < n) s += deg[idx];
  }
  #pragma unroll
  for (int off = 32; off; off >>= 1) s += __shfl_down(s, off);
  if ((t & 63) == 0) ws[t >> 6] = s;
  __syncthreads();
  if (t == 0) bsum[blockIdx.x] = ws[0] + ws[1] + ws[2] + ws[3];
}

// single 64-thread block; nb <= 64. boff = exclusive scan; *row_n = total.
__global__ void scan2_kernel(const int* __restrict__ bsum, int* __restrict__ boff,
                             int* __restrict__ row_n, int nb) {
  int t = threadIdx.x;
  int mine = (t < nb) ? bsum[t] : 0;
  int v = mine;
  #pragma unroll
  for (int off = 1; off < 64; off <<= 1) {
    int u = __shfl_up(v, off);
    if (t >= off) v += u;
  }
  if (t < nb) boff[t] = v - mine;
  if (t == nb - 1) *row_n = v;
}

__global__ __launch_bounds__(256) void scan3_kernel(const int* __restrict__ deg,
                                                    const int* __restrict__ boff,
                                                    int* __restrict__ row_start,
                                                    int* __restrict__ cursor, int n) {
  __shared__ int lsum[256];
  int t = threadIdx.x;
  int base = blockIdx.x * 2048 + t * 8;
  int loc[8];
  int s = 0;
  #pragma unroll
  for (int i = 0; i < 8; ++i) {
    int idx = base + i;
    int d = (idx < n) ? deg[idx] : 0;
    loc[i] = s;
    s += d;
  }
  lsum[t] = s;
  __syncthreads();
  #pragma unroll
  for (int off = 1; off < 256; off <<= 1) {
    int v2 = (t >= off) ? lsum[t - off] : 0;
    __syncthreads();
    lsum[t] += v2;
    __syncthreads();
  }
  int toff = boff[blockIdx.x] + lsum[t] - s;  // exclusive across grid
  #pragma unroll
  for (int i = 0; i < 8; ++i) {
    int idx = base + i;
    if (idx < n) {
      int rs = toff + loc[i];
      row_start[idx] = rs;
      cursor[idx] = rs;
    }
  }
}

// pack {src, f16 edge_attr pairs} into CSR position (once; reused all 5 layers)
__global__ void fill_kernel(const int* __restrict__ ei, int* __restrict__ cursor,
                            const float* __restrict__ eattr,
                            EPack* __restrict__ epk, int E) {
  int e = blockIdx.x * blockDim.x + threadIdx.x;
  if (e < E) {
    int d = ei[E + e];
    int pos = atomicAdd(&cursor[d], 1);
    EPack r;
    r.src = ei[e];
    const float* ea = eattr + (size_t)e * 10;
    #pragma unroll
    for (int k2 = 0; k2 < 5; ++k2) {
      union { uint u; half2v h; } cv;
      cv.h[0] = (_Float16)ea[2 * k2];
      cv.h[1] = (_Float16)ea[2 * k2 + 1];
      r.ea2[k2] = cv.u;
    }
    r.pad[0] = r.pad[1] = 0;
    epk[pos] = r;
  }
}

// graph_start[g] = lower_bound(batch, g); batch is sorted. Handles empty graphs.
__global__ void bounds_kernel(const int* __restrict__ batch, int* __restrict__ gstart,
                              int n, int ng) {
  int g = blockIdx.x * blockDim.x + threadIdx.x;
  if (g > ng) return;
  int lo = 0, hi = n;
  while (lo < hi) {
    int mid = (lo + hi) >> 1;
    if (batch[mid] < g) lo = mid + 1; else hi = mid;
  }
  gstart[g] = lo;
}

// W [L][K][N] -> Wth [L][N][K] (transpose + bf16 round), per flat idx
__global__ void wtrans_kernel(const float* __restrict__ W, ushort* __restrict__ Wth,
                              int K, int N, int total) {
  int idx = blockIdx.x * blockDim.x + threadIdx.x;
  if (idx >= total) return;
  int kk = idx % K;
  int t = idx / K;
  int nn = t % N;
  int l = t / N;
  Wth[idx] = f2bf(W[((size_t)l * K + kk) * N + nn]);
}

// h0 = x @ node_W + node_b   (K=9, N=128)
__global__ void encoder_kernel(const float* __restrict__ x, const float* __restrict__ W,
                               const float* __restrict__ b, float* __restrict__ h0, int n) {
  __shared__ float Ws[9][EMB];
  __shared__ float bs[EMB];
  int t = threadIdx.x;
  if (t < EMB) {
    #pragma unroll
    for (int k = 0; k < 9; ++k) Ws[k][t] = W[k * EMB + t];
    bs[t] = b[t];
  }
  __syncthreads();
  int total = n * EMB;
  for (int idx = blockIdx.x * blockDim.x + t; idx < total; idx += gridDim.x * blockDim.x) {
    int i = idx >> 7, j = idx & 127;
    const float* xr = x + i * 9;
    float acc = bs[j];
    #pragma unroll
    for (int k = 0; k < 9; ++k) acc = fmaf(xr[k], Ws[k][j], acc);
    h0[idx] = acc;
  }
}

// ---------------- per-layer kernels ----------------

// h_in = (RAW ? src : relu(bn2(src))) + vn[batch]; also writes bf16 copy h16
// float4-vectorized: 4 consecutive channels per thread.
template <bool RAW>
__global__ void hin_kernel(const float* __restrict__ src, const float* __restrict__ vn,
                           const int* __restrict__ batch, const float* __restrict__ s2raw,
                           const float* __restrict__ g2, const float* __restrict__ b2,
                           float* __restrict__ h_in, ushort* __restrict__ h16, int n) {
  __shared__ float sc[EMB], sh[EMB];
  if (!RAW) {
    int j = threadIdx.x;
    if (j < EMB) {
      float s = s2raw[j], q = s2raw[EMB + j];
      float mean = s / (float)n;
      float var = q / (float)n - mean * mean;
      float scl = g2[j] * rsqrtf(var + BN_EPS);
      sc[j] = scl;
      sh[j] = b2[j] - mean * scl;
    }
    __syncthreads();
  }
  int total4 = n * (EMB / 4);
  for (int idx = blockIdx.x * blockDim.x + threadIdx.x; idx < total4; idx += gridDim.x * blockDim.x) {
    int i = idx >> 5;
    int j4 = (idx & 31) << 2;
    float4 v = *reinterpret_cast<const float4*>(src + (size_t)i * EMB + j4);
    if (!RAW) {
      v.x = fmaxf(fmaf(v.x, sc[j4 + 0], sh[j4 + 0]), 0.f);
      v.y = fmaxf(fmaf(v.y, sc[j4 + 1], sh[j4 + 1]), 0.f);
      v.z = fmaxf(fmaf(v.z, sc[j4 + 2], sh[j4 + 2]), 0.f);
      v.w = fmaxf(fmaf(v.w, sc[j4 + 3], sh[j4 + 3]), 0.f);
    }
    float4 vv = *reinterpret_cast<const float4*>(vn + (size_t)batch[i] * EMB + j4);
    v.x += vv.x; v.y += vv.y; v.z += vv.z; v.w += vv.w;
    *reinterpret_cast<float4*>(h_in + (size_t)i * EMB + j4) = v;
    ushort4 h;
    h.x = f2bf(v.x); h.y = f2bf(v.y); h.z = f2bf(v.z); h.w = f2bf(v.w);
    *reinterpret_cast<ushort4*>(h16 + (size_t)i * EMB + j4) = h;
  }
}

// final output: d_out = bn2(t2)  (no relu, layer L-1); float4-vectorized
__global__ void out_kernel(const float* __restrict__ t2, const float* __restrict__ s2raw,
                           const float* __restrict__ g2, const float* __restrict__ b2,
                           float* __restrict__ out, int n) {
  __shared__ float sc[EMB], sh[EMB];
  int j0 = threadIdx.x;
  if (j0 < EMB) {
    float s = s2raw[j0], q = s2raw[EMB + j0];
    float mean = s / (float)n;
    float var = q / (float)n - mean * mean;
    float scl = g2[j0] * rsqrtf(var + BN_EPS);
    sc[j0] = scl;
    sh[j0] = b2[j0] - mean * scl;
  }
  __syncthreads();
  int total4 = n * (EMB / 4);
  for (int idx = blockIdx.x * blockDim.x + threadIdx.x; idx < total4; idx += gridDim.x * blockDim.x) {
    int i = idx >> 5;
    int j4 = (idx & 31) << 2;
    float4 v = *reinterpret_cast<const float4*>(t2 + (size_t)i * EMB + j4);
    v.x = fmaf(v.x, sc[j4 + 0], sh[j4 + 0]);
    v.y = fmaf(v.y, sc[j4 + 1], sh[j4 + 1]);
    v.z = fmaf(v.z, sc[j4 + 2], sh[j4 + 2]);
    v.w = fmaf(v.w, sc[j4 + 3], sh[j4 + 3]);
    *reinterpret_cast<float4*>(out + (size_t)i * EMB + j4) = v;
  }
}

// vnsum partials: grid (NGR, 4); chunk c of graph g -> vnsum4[c][g][:]
__global__ void vnsum_kernel(const float* __restrict__ h_in, const int* __restrict__ gstart,
                             float* __restrict__ vnsum4) {
  int g = blockIdx.x;
  int c = blockIdx.y;
  int j = threadIdx.x;
  int s0 = gstart[g], s1 = gstart[g + 1];
  int chunk = (s1 - s0 + 3) >> 2;
  int a = s0 + c * chunk;
  int b = min(s1, a + chunk);
  float acc = 0.f;
  for (int i = a; i < b; ++i) acc += h_in[(size_t)i * EMB + j];
  vnsum4[((size_t)c * NGR + g) * EMB + j] = acc;
}

// t_pre[i] = (1+eps)*h_in[i] + sum_{e: dst=i} relu(h16[src(e)] + ea(e) @ eW + eb)
// Grid-stride (~6 nodes/block, W staged once). fdot2 edge encoder.
__global__ __launch_bounds__(128) void agg_kernel(
    const float* __restrict__ h_in, const ushort* __restrict__ h16,
    const int* __restrict__ row_start, const EPack* __restrict__ epk,
    const float* __restrict__ eW, const float* __restrict__ eb,
    const float* __restrict__ eps_p, int l,
    ushort* __restrict__ tpre_h, ushort* __restrict__ tpre_l, int n) {
  __shared__ uint Wp[5][EMB];       // packed half2 weight pairs
  __shared__ float bia[EMB];
  int j = threadIdx.x;  // 128
  #pragma unroll
  for (int k2 = 0; k2 < 5; ++k2) {
    union { uint u; half2v h; } cv;
    cv.h[0] = (_Float16)eW[(2 * k2) * EMB + j];
    cv.h[1] = (_Float16)eW[(2 * k2 + 1) * EMB + j];
    Wp[k2][j] = cv.u;
  }
  bia[j] = eb[j];
  float epsv = 1.f + eps_p[l];
  __syncthreads();

  for (int i = blockIdx.x; i < n; i += gridDim.x) {
    int s0 = row_start[i], s1 = row_start[i + 1];
    float acc = epsv * h_in[(size_t)i * EMB + j];
    int p = s0;

    auto edot = [&](const EPack* ep) -> float {
      float v = bia[j];
      #pragma unroll
      for (int k2 = 0; k2 < 5; ++k2) {
        union { uint u; half2v h; } a, w;
        a.u = ep->ea2[k2];
        w.u = Wp[k2][j];
#ifdef HAS_FDOT2
        v = __builtin_amdgcn_fdot2(a.h, w.h, v, false);
#else
        v = fmaf((float)a.h[0], (float)w.h[0], v);
        v = fmaf((float)a.h[1], (float)w.h[1], v);
#endif
      }
      return v;
    };

    for (; p + 8 <= s1; p += 8) {
      int srcs[8];
      #pragma unroll
      for (int u = 0; u < 8; ++u) srcs[u] = epk[p + u].src;
      float hv[8];
      #pragma unroll
      for (int u = 0; u < 8; ++u) hv[u] = bf2f(h16[(size_t)srcs[u] * EMB + j]);
      #pragma unroll
      for (int u = 0; u < 8; ++u)
        acc += fmaxf(edot(epk + p + u) + hv[u], 0.f);
    }
    for (; p + 4 <= s1; p += 4) {
      int srcs[4];
      #pragma unroll
      for (int u = 0; u < 4; ++u) srcs[u] = epk[p + u].src;
      float hv[4];
      #pragma unroll
      for (int u = 0; u < 4; ++u) hv[u] = bf2f(h16[(size_t)srcs[u] * EMB + j]);
      #pragma unroll
      for (int u = 0; u < 4; ++u)
        acc += fmaxf(edot(epk + p + u) + hv[u], 0.f);
    }
    for (; p < s1; ++p) {
      float hv0 = bf2f(h16[(size_t)epk[p].src * EMB + j]);
      acc += fmaxf(edot(epk + p) + hv0, 0.f);
    }
    ushort hh = f2bf(acc);
    tpre_h[(size_t)i * EMB + j] = hh;
    tpre_l[(size_t)i * EMB + j] = f2bf(acc - bf2f(hh));
  }
}

// ---------------- bf16x2 split-MFMA GEMM (A hi+lo, B bf16) ----------------
// APRE: A supplied pre-split (Ath/Atl). Else A fp32 with optional BN+relu,
// split during staging. D = Ah@Bh + Al@Bh (weights bf16-rounded).
template <int KT, int NT, bool BN_A, bool STATS, bool APRE>
__global__ __launch_bounds__(256) void gemm_mfma(
    const float* __restrict__ A, const ushort* __restrict__ Ath,
    const ushort* __restrict__ Atl,
    const ushort* __restrict__ Bth,
    const float* __restrict__ bias,
    float* __restrict__ C, int M,
    const float* __restrict__ bnraw, const float* __restrict__ bng,
    const float* __restrict__ bnb, float* __restrict__ statraw) {
  constexpr int BM = 128, BN = 128, BK = 32;
  constexpr int LDK = BK + 8;
  constexpr int KSTEPS = KT / BK;
  __shared__ ushort Ah[BM][LDK], Al[BM][LDK];
  __shared__ ushort Bh[BN][LDK];
  __shared__ float red[8][BN], redq[8][BN];
  constexpr int SCN = BN_A ? KT : 1;
  __shared__ float scS[SCN], shS[SCN];

  int tid = threadIdx.x;
  if (BN_A) {
    for (int k = tid; k < KT; k += 256) {
      float s = bnraw[k], q = bnraw[KT + k];
      float mean = s / (float)M;
      float var = q / (float)M - mean * mean;
      float scl = bng[k] * rsqrtf(var + BN_EPS);
      scS[k] = scl;
      shS[k] = bnb[k] - mean * scl;
    }
  }

  int wv = tid >> 6, lane = tid & 63;
  int wr = wv >> 1, wc = wv & 1;
  int lr = lane & 15, kg = lane >> 4;
  int bm0 = blockIdx.x * BM;
  int gc0 = blockIdx.y * BN;

  int sr = tid >> 1;
  int skq = (tid & 1) * 16;

  f32x4 acc[4][4];
  #pragma unroll
  for (int fm = 0; fm < 4; ++fm)
    #pragma unroll
    for (int fn = 0; fn < 4; ++fn) {
      float b = bias[gc0 + wc * 64 + fn * 16 + lr];
      acc[fm][fn][0] = b; acc[fm][fn][1] = b; acc[fm][fn][2] = b; acc[fm][fn][3] = b;
    }

  for (int kt = 0; kt < KSTEPS; ++kt) {
    __syncthreads();
    {
      int grow = bm0 + sr;
      if (APRE) {
        short8v z;
        #pragma unroll
        for (int q2 = 0; q2 < 8; ++q2) z[q2] = 0;
        if (grow < M) {
          const ushort* aph = Ath + (size_t)grow * KT + kt * BK + skq;
          const ushort* apl = Atl + (size_t)grow * KT + kt * BK + skq;
          *(short8v*)&Ah[sr][skq] = *(const short8v*)aph;
          *(short8v*)&Ah[sr][skq + 8] = *(const short8v*)(aph + 8);
          *(short8v*)&Al[sr][skq] = *(const short8v*)apl;
          *(short8v*)&Al[sr][skq + 8] = *(const short8v*)(apl + 8);
        } else {
          *(short8v*)&Ah[sr][skq] = z;
          *(short8v*)&Ah[sr][skq + 8] = z;
          *(short8v*)&Al[sr][skq] = z;
          *(short8v*)&Al[sr][skq + 8] = z;
        }
      } else {
        const float* ap = A + (size_t)grow * KT + kt * BK + skq;
        short8v ah0, al0, ah1, al1;
        #pragma unroll
        for (int u = 0; u < 4; ++u) {
          float4 v = (grow < M) ? *reinterpret_cast<const float4*>(ap + u * 4)
                                : make_float4(0.f, 0.f, 0.f, 0.f);
          if (BN_A) {
            int gk = kt * BK + skq + u * 4;
            v.x = fmaxf(fmaf(v.x, scS[gk + 0], shS[gk + 0]), 0.f);
            v.y = fmaxf(fmaf(v.y, scS[gk + 1], shS[gk + 1]), 0.f);
            v.z = fmaxf(fmaf(v.z, scS[gk + 2], shS[gk + 2]), 0.f);
            v.w = fmaxf(fmaf(v.w, scS[gk + 3], shS[gk + 3]), 0.f);
          }
          float vv0 = v.x, vv1 = v.y, vv2 = v.z, vv3 = v.w;
          ushort h0 = f2bf(vv0), h1 = f2bf(vv1), h2 = f2bf(vv2), h3 = f2bf(vv3);
          ushort w0 = f2bf(vv0 - bf2f(h0)), w1 = f2bf(vv1 - bf2f(h1));
          ushort w2 = f2bf(vv2 - bf2f(h2)), w3 = f2bf(vv3 - bf2f(h3));
          if (u < 2) {
            ah0[u * 4 + 0] = (short)h0; ah0[u * 4 + 1] = (short)h1;
            ah0[u * 4 + 2] = (short)h2; ah0[u * 4 + 3] = (short)h3;
            al0[u * 4 + 0] = (short)w0; al0[u * 4 + 1] = (short)w1;
            al0[u * 4 + 2] = (short)w2; al0[u * 4 + 3] = (short)w3;
          } else {
            ah1[(u - 2) * 4 + 0] = (short)h0; ah1[(u - 2) * 4 + 1] = (short)h1;
            ah1[(u - 2) * 4 + 2] = (short)h2; ah1[(u - 2) * 4 + 3] = (short)h3;
            al1[(u - 2) * 4 + 0] = (short)w0; al1[(u - 2) * 4 + 1] = (short)w1;
            al1[(u - 2) * 4 + 2] = (short)w2; al1[(u - 2) * 4 + 3] = (short)w3;
          }
        }
        *(short8v*)&Ah[sr][skq] = ah0;
        *(short8v*)&Ah[sr][skq + 8] = ah1;
        *(short8v*)&Al[sr][skq] = al0;
        *(short8v*)&Al[sr][skq + 8] = al1;
      }
    }
    {
      const ushort* bph = Bth + (size_t)(gc0 + sr) * KT + kt * BK + skq;
      *(short8v*)&Bh[sr][skq] = *(const short8v*)bph;
      *(short8v*)&Bh[sr][skq + 8] = *(const short8v*)(bph + 8);
    }
    __syncthreads();
    short8v a_h[4], a_l[4], b_h[4];
    #pragma unroll
    for (int f = 0; f < 4; ++f) {
      a_h[f] = *(const short8v*)&Ah[wr * 64 + f * 16 + lr][kg * 8];
      a_l[f] = *(const short8v*)&Al[wr * 64 + f * 16 + lr][kg * 8];
      b_h[f] = *(const short8v*)&Bh[wc * 64 + f * 16 + lr][kg * 8];
    }
    #pragma unroll
    for (int fm = 0; fm < 4; ++fm)
      #pragma unroll
      for (int fn = 0; fn < 4; ++fn) {
        acc[fm][fn] = __builtin_amdgcn_mfma_f32_16x16x32_bf16(a_h[fm], b_h[fn], acc[fm][fn], 0, 0, 0);
        acc[fm][fn] = __builtin_amdgcn_mfma_f32_16x16x32_bf16(a_l[fm], b_h[fn], acc[fm][fn], 0, 0, 0);
      }
  }

  #pragma unroll
  for (int fm = 0; fm < 4; ++fm) {
    int rb = bm0 + wr * 64 + fm * 16 + kg * 4;
    #pragma unroll
    for (int i = 0; i < 4; ++i) {
      int grow = rb + i;
      if (grow < M) {
        float* cp = C + (size_t)grow * NT + gc0 + wc * 64 + lr;
        #pragma unroll
        for (int fn = 0; fn < 4; ++fn) cp[fn * 16] = acc[fm][fn][i];
      }
    }
  }

  if (STATS) {
    #pragma unroll
    for (int fn = 0; fn < 4; ++fn) {
      float s = 0.f, q = 0.f;
      #pragma unroll
      for (int fm = 0; fm < 4; ++fm) {
        int rb = bm0 + wr * 64 + fm * 16 + kg * 4;
        #pragma unroll
        for (int i = 0; i < 4; ++i) {
          if (rb + i < M) {
            float v = acc[fm][fn][i];
            s += v;
            q = fmaf(v, v, q);
          }
        }
      }
      red[wr * 4 + kg][wc * 64 + fn * 16 + lr] = s;
      redq[wr * 4 + kg][wc * 64 + fn * 16 + lr] = q;
    }
    __syncthreads();
    if (tid < BN) {
      float s = 0.f, q = 0.f;
      #pragma unroll
      for (int r2 = 0; r2 < 8; ++r2) {
        s += red[r2][tid];
        q += redq[r2][tid];
      }
      int gcol = gc0 + tid;
      atomicAdd(&statraw[gcol], s);
      atomicAdd(&statraw[NT + gcol], q);
    }
  }
}

// ---------------- virtual-node MLP (tiny: 512 rows) ----------------

// u1[g] = (vn[g] + sum4 partials) @ W(128x256) + b ; fused stats
__global__ void vmlp1_kernel(const float* __restrict__ vnsum4, const float* __restrict__ vn,
                             const float* __restrict__ W,
                             const float* __restrict__ b, float* __restrict__ u1,
                             float* __restrict__ vs1raw) {
  __shared__ float a[EMB];
  int g = blockIdx.x;
  int j = threadIdx.x;  // 256
  if (j < EMB) {
    float s = vn[g * EMB + j];
    #pragma unroll
    for (int c = 0; c < 4; ++c) s += vnsum4[((size_t)c * NGR + g) * EMB + j];
    a[j] = s;
  }
  __syncthreads();
  float acc = b[j];
  #pragma unroll 8
  for (int k = 0; k < EMB; ++k) acc = fmaf(a[k], W[k * 256 + j], acc);
  u1[g * 256 + j] = acc;
  atomicAdd(&vs1raw[j], acc);
  atomicAdd(&vs1raw[256 + j], acc * acc);
}

__global__ void vmlp2_kernel(const float* __restrict__ u1, const float* __restrict__ vs1raw,
                             const float* __restrict__ g1, const float* __restrict__ b1,
                             const float* __restrict__ W, const float* __restrict__ b2,
                             float* __restrict__ u2, float* __restrict__ vs2raw) {
  __shared__ float a[256];
  __shared__ float sc[256], sh[256];
  int g = blockIdx.x;
  int j = threadIdx.x;  // 128
  for (int k = j; k < 256; k += EMB) {
    float s = vs1raw[k], q = vs1raw[256 + k];
    float mean = s / (float)NGR;
    float var = q / (float)NGR - mean * mean;
    float scl = g1[k] * rsqrtf(var + BN_EPS);
    sc[k] = scl;
    sh[k] = b1[k] - mean * scl;
  }
  __syncthreads();
  for (int k = j; k < 256; k += EMB)
    a[k] = fmaxf(fmaf(u1[g * 256 + k], sc[k], sh[k]), 0.f);
  __syncthreads();
  float acc = b2[j];
  #pragma unroll 8
  for (int k = 0; k < 256; ++k) acc = fmaf(a[k], W[k * EMB + j], acc);
  u2[g * EMB + j] = acc;
  atomicAdd(&vs2raw[j], acc);
  atomicAdd(&vs2raw[EMB + j], acc * acc);
}

__global__ void vnupd_kernel(const float* __restrict__ u2, const float* __restrict__ vs2raw,
                             const float* __restrict__ g2, const float* __restrict__ b2,
                             float* __restrict__ vn) {
  __shared__ float sc[EMB], sh[EMB];
  int g = blockIdx.x;
  int j = threadIdx.x;  // 128
  {
    float s = vs2raw[j], q = vs2raw[EMB + j];
    float mean = s / (float)NGR;
    float var = q / (float)NGR - mean * mean;
    float scl = g2[j] * rsqrtf(var + BN_EPS);
    sc[j] = scl;
    sh[j] = b2[j] - mean * scl;
  }
  __syncthreads();
  vn[g * EMB + j] = fmaxf(fmaf(u2[g * EMB + j], sc[j], sh[j]), 0.f);
}

// ---------------- host launcher ----------------

extern "C" void kernel_launch(void* const* d_in, const int* in_sizes, int n_in,
                              void* d_out, int out_size, void* d_ws, size_t ws_size,
                              hipStream_t stream) {
  const float* x        = (const float*)d_in[0];
  const int*   ei       = (const int*)d_in[1];
  const float* eattr    = (const float*)d_in[2];
  const int*   batch    = (const int*)d_in[3];
  const float* node_W   = (const float*)d_in[4];
  const float* node_b   = (const float*)d_in[5];
  const float* vn_emb   = (const float*)d_in[6];
  const float* eps      = (const float*)d_in[7];
  const float* edge_W   = (const float*)d_in[8];
  const float* edge_b   = (const float*)d_in[9];
  const float* conv_W1  = (const float*)d_in[10];
  const float* conv_b1  = (const float*)d_in[11];
  const float* cbn_g    = (const float*)d_in[12];
  const float* cbn_b    = (const float*)d_in[13];
  const float* conv_W2  = (const float*)d_in[14];
  const float* conv_b2  = (const float*)d_in[15];
  const float* bn_g     = (const float*)d_in[16];
  const float* bn_b     = (const float*)d_in[17];
  const float* vW1      = (const float*)d_in[18];
  const float* vb1      = (const float*)d_in[19];
  const float* vbn1_g   = (const float*)d_in[20];
  const float* vbn1_b   = (const float*)d_in[21];
  const float* vW2      = (const float*)d_in[22];
  const float* vb2      = (const float*)d_in[23];
  const float* vbn2_g   = (const float*)d_in[24];
  const float* vbn2_b   = (const float*)d_in[25];

  const int n = in_sizes[0] / 9;   // 50000
  const int E = in_sizes[1] / 2;   // 600000
  const int nb = (n + 2047) / 2048;

  // -------- workspace carve (aligned 256B) --------
  char* p = (char*)d_ws;
  auto carve = [&](size_t bytes) {
    char* r = p;
    p += (bytes + 255) & ~(size_t)255;
    return r;
  };
  float* h_in   = (float*)carve((size_t)n * EMB * 4);
  ushort* h16   = (ushort*)carve((size_t)n * EMB * 2);
  float* t1     = (float*)carve((size_t)n * 256 * 4);
  float* t2     = (float*)carve((size_t)n * EMB * 4);
  ushort* tpre_h = (ushort*)carve((size_t)n * EMB * 2);
  ushort* tpre_l = (ushort*)carve((size_t)n * EMB * 2);
  float* vn     = (float*)carve((size_t)NGR * EMB * 4);
  float* vnsum4 = (float*)carve((size_t)4 * NGR * EMB * 4);
  float* u1     = (float*)carve((size_t)NGR * 256 * 4);
  float* u2     = (float*)carve((size_t)NGR * EMB * 4);
  float* stats  = (float*)carve((size_t)NLAYER * 1536 * 4);
  int* deg      = (int*)carve((size_t)n * 4);
  int* rstart   = (int*)carve((size_t)(n + 1) * 4);
  int* cursor   = (int*)carve((size_t)n * 4);
  EPack* epk    = (EPack*)carve((size_t)E * sizeof(EPack));
  int* gstart   = (int*)carve((size_t)(NGR + 1) * 4);
  int* bsum     = (int*)carve((size_t)64 * 4);
  int* boff     = (int*)carve((size_t)64 * 4);
  ushort* wt1h  = (ushort*)carve((size_t)NLAYER * 256 * 128 * 2);
  ushort* wt2h  = (ushort*)carve((size_t)NLAYER * 128 * 256 * 2);
  float* h0     = t1;  // alias: h0 consumed (by l=0 hin) before t1 written

  auto s1  = [&](int l) { return stats + (size_t)l * 1536; };
  auto s2  = [&](int l) { return stats + (size_t)l * 1536 + 512; };
  auto vs1 = [&](int l) { return stats + (size_t)l * 1536 + 768; };
  auto vs2 = [&](int l) { return stats + (size_t)l * 1536 + 1280; };

  // -------- setup --------
  init_kernel<<<(NGR * EMB + 255) / 256, 256, 0, stream>>>(deg, n, stats, NLAYER * 1536, vn, vn_emb);
  deg_kernel<<<(E + 255) / 256, 256, 0, stream>>>(ei, deg, E);
  scan1_kernel<<<nb, 256, 0, stream>>>(deg, bsum, n);
  scan2_kernel<<<1, 64, 0, stream>>>(bsum, boff, rstart + n, nb);
  scan3_kernel<<<nb, 256, 0, stream>>>(deg, boff, rstart, cursor, n);
  fill_kernel<<<(E + 255) / 256, 256, 0, stream>>>(ei, cursor, eattr, epk, E);
  bounds_kernel<<<(NGR + 1 + 255) / 256, 256, 0, stream>>>(batch, gstart, n, NGR);
  {
    int tot1 = NLAYER * 128 * 256;   // conv_W1: K=128, N=256
    wtrans_kernel<<<(tot1 + 255) / 256, 256, 0, stream>>>(conv_W1, wt1h, 128, 256, tot1);
    int tot2 = NLAYER * 256 * 128;   // conv_W2: K=256, N=128
    wtrans_kernel<<<(tot2 + 255) / 256, 256, 0, stream>>>(conv_W2, wt2h, 256, 128, tot2);
  }
  encoder_kernel<<<2048, 256, 0, stream>>>(x, node_W, node_b, h0, n);

  const int mtiles = (n + 127) / 128;

  for (int l = 0; l < NLAYER; ++l) {
    if (l == 0)
      hin_kernel<true><<<4096, 256, 0, stream>>>(h0, vn, batch, nullptr, nullptr, nullptr,
                                                 h_in, h16, n);
    else
      hin_kernel<false><<<4096, 256, 0, stream>>>(t2, vn, batch, s2(l - 1),
                                                  bn_g + (size_t)(l - 1) * EMB,
                                                  bn_b + (size_t)(l - 1) * EMB, h_in, h16, n);
    if (l < NLAYER - 1)
      vnsum_kernel<<<dim3(NGR, 4), EMB, 0, stream>>>(h_in, gstart, vnsum4);

    agg_kernel<<<8192, EMB, 0, stream>>>(h_in, h16, rstart, epk,
                                         edge_W + (size_t)l * 10 * EMB,
                                         edge_b + (size_t)l * EMB, eps, l, tpre_h, tpre_l, n);

    gemm_mfma<128, 256, false, true, true><<<dim3(mtiles, 2), 256, 0, stream>>>(
        nullptr, tpre_h, tpre_l, wt1h + (size_t)l * 256 * 128,
        conv_b1 + (size_t)l * 256, t1, n, nullptr, nullptr, nullptr, s1(l));

    gemm_mfma<256, 128, true, true, false><<<dim3(mtiles, 1), 256, 0, stream>>>(
        t1, nullptr, nullptr, wt2h + (size_t)l * 128 * 256,
        conv_b2 + (size_t)l * 128, t2, n,
        s1(l), cbn_g + (size_t)l * 256, cbn_b + (size_t)l * 256, s2(l));

    if (l < NLAYER - 1) {
      vmlp1_kernel<<<NGR, 256, 0, stream>>>(vnsum4, vn, vW1 + (size_t)l * 128 * 256,
                                            vb1 + (size_t)l * 256, u1, vs1(l));
      vmlp2_kernel<<<NGR, EMB, 0, stream>>>(u1, vs1(l), vbn1_g + (size_t)l * 256,
                                            vbn1_b + (size_t)l * 256,
                                            vW2 + (size_t)l * 256 * 128,
                                            vb2 + (size_t)l * EMB, u2, vs2(l));
      vnupd_kernel<<<NGR, EMB, 0, stream>>>(u2, vs2(l), vbn2_g + (size_t)l * EMB,
                                            vbn2_b + (size_t)l * EMB, vn);
    }
  }

  out_kernel<<<4096, 256, 0, stream>>>(t2, s2(NLAYER - 1),
                                       bn_g + (size_t)(NLAYER - 1) * EMB,
                                       bn_b + (size_t)(NLAYER - 1) * EMB,
                                       (float*)d_out, n);
}